// Round 2
// baseline (5365.448 us; speedup 1.0000x reference)
//
#include <hip/hip_runtime.h>
#include <hip/hip_bf16.h>

__device__ __forceinline__ float wave_sum(float v) {
    #pragma unroll
    for (int off = 32; off; off >>= 1) v += __shfl_xor(v, off);
    return v;
}
__device__ __forceinline__ float wave_max(float v) {
    #pragma unroll
    for (int off = 32; off; off >>= 1) v = fmaxf(v, __shfl_xor(v, off));
    return v;
}

// ---------------------------------------------------------------------------
// Generic tiled GEMM: C[M,N] = act(A[M,K] @ B[K,N] + bias[N])
// All fp32. M,N multiples of 64; K multiple of 16; lda/ldb multiples of 4.
// 64x64 tile per 256-thread block, 4x4 per thread.
// ---------------------------------------------------------------------------
__global__ __launch_bounds__(256) void gemm_tile(
    const float* __restrict__ A, int lda,
    const float* __restrict__ Bm, int ldb,
    const float* __restrict__ bias,
    float* __restrict__ C, int ldc,
    int K, int act)
{
    __shared__ float As[16][68];  // A^T tile: [k][row], padded
    __shared__ float Bs[16][64];  // [k][col]

    const int tid = threadIdx.x;
    const int tx = tid & 15, ty = tid >> 4;
    const int rowBase = blockIdx.y * 64, colBase = blockIdx.x * 64;

    const int ar = tid >> 2;          // 0..63 : tile row
    const int ak = (tid & 3) << 2;    // 0,4,8,12 : k offset (4 contiguous)
    const int bk = tid >> 4;          // 0..15 : tile k row
    const int bc = (tid & 15) << 2;   // 0..60 : col offset (4 contiguous)

    float acc[4][4] = {};

    const float* aptr = A  + (size_t)(rowBase + ar) * lda + ak;
    const float* bptr = Bm + (size_t)bk * ldb + colBase + bc;

    for (int kt = 0; kt < K; kt += 16) {
        const float4 a4 = *(const float4*)aptr;
        const float4 b4 = *(const float4*)bptr;
        As[ak + 0][ar] = a4.x; As[ak + 1][ar] = a4.y; As[ak + 2][ar] = a4.z; As[ak + 3][ar] = a4.w;
        *(float4*)&Bs[bk][bc] = b4;
        __syncthreads();
        #pragma unroll
        for (int kk = 0; kk < 16; ++kk) {
            const float4 av = *(const float4*)&As[kk][ty << 2];
            const float4 bv = *(const float4*)&Bs[kk][tx << 2];
            acc[0][0] += av.x * bv.x; acc[0][1] += av.x * bv.y; acc[0][2] += av.x * bv.z; acc[0][3] += av.x * bv.w;
            acc[1][0] += av.y * bv.x; acc[1][1] += av.y * bv.y; acc[1][2] += av.y * bv.z; acc[1][3] += av.y * bv.w;
            acc[2][0] += av.z * bv.x; acc[2][1] += av.z * bv.y; acc[2][2] += av.z * bv.z; acc[2][3] += av.z * bv.w;
            acc[3][0] += av.w * bv.x; acc[3][1] += av.w * bv.y; acc[3][2] += av.w * bv.z; acc[3][3] += av.w * bv.w;
        }
        __syncthreads();
        aptr += 16;
        bptr += (size_t)16 * ldb;
    }

    #pragma unroll
    for (int rr = 0; rr < 4; ++rr) {
        const int row = rowBase + (ty << 2) + rr;
        float* crow = C + (size_t)row * ldc + colBase + (tx << 2);
        #pragma unroll
        for (int cc = 0; cc < 4; ++cc) {
            float v = acc[rr][cc] + bias[colBase + (tx << 2) + cc];
            if (act) v = fmaxf(v, 0.f);
            crow[cc] = v;
        }
    }
}

// ---------------------------------------------------------------------------
// pe[s,d]: d even -> sin(s*div), odd -> cos(s*div); div = exp((d&~1)*(-ln1e4/512))
// ---------------------------------------------------------------------------
__global__ void pe_kernel(float* __restrict__ pe)
{
    int idx = blockIdx.x * 256 + threadIdx.x;   // 1024*512 total
    int s = idx >> 9, d = idx & 511;
    float div = expf((float)(d & ~1) * (-9.210340371976184f / 512.0f));
    float ang = (float)s * div;
    pe[idx] = (d & 1) ? cosf(ang) : sinf(ang);
}

// y = qa_embed + pe (broadcast over batch)
__global__ void y_kernel(const float* __restrict__ qa, const float* __restrict__ pe,
                         float* __restrict__ y)
{
    int idx = blockIdx.x * 256 + threadIdx.x;   // 4096*512 total
    y[idx] = qa[idx] + pe[idx & 524287];
}

// ---------------------------------------------------------------------------
// Gate: logits = [summary | m_seq] @ gate_w + gate_b; top-2 masked softmax.
// One wave per row (of 4096).
// ---------------------------------------------------------------------------
__global__ __launch_bounds__(64) void gate_kernel(
    const float* __restrict__ summary, const float* __restrict__ m_seq,
    const float* __restrict__ gw, const float* __restrict__ gb,
    float* __restrict__ gates)
{
    const int r = blockIdx.x, t = threadIdx.x;
    float p0 = 0.f, p1 = 0.f, p2 = 0.f, p3 = 0.f;
    const float* srow = summary + (size_t)r * 512;
    for (int j = t; j < 512; j += 64) {
        float s = srow[j];
        const float* g = gw + (size_t)j * 4;
        p0 += s * g[0]; p1 += s * g[1]; p2 += s * g[2]; p3 += s * g[3];
    }
    {   // SD = 64: one element per lane
        float m = m_seq[(size_t)r * 64 + t];
        const float* g = gw + (size_t)(512 + t) * 4;
        p0 += m * g[0]; p1 += m * g[1]; p2 += m * g[2]; p3 += m * g[3];
    }
    p0 = wave_sum(p0); p1 = wave_sum(p1); p2 = wave_sum(p2); p3 = wave_sum(p3);
    if (t == 0) {
        float lg[4] = { p0 + gb[0], p1 + gb[1], p2 + gb[2], p3 + gb[3] };
        float m1 = -INFINITY, m2 = -INFINITY;
        #pragma unroll
        for (int k = 0; k < 4; ++k) {
            float v = lg[k];
            if (v > m1) { m2 = m1; m1 = v; }
            else if (v > m2) { m2 = v; }
        }
        float wv[4], s = 0.f;
        #pragma unroll
        for (int k = 0; k < 4; ++k) {
            wv[k] = (lg[k] >= m2) ? __expf(lg[k] - m1) : 0.f;
            s += wv[k];
        }
        float inv = 1.f / s;
        #pragma unroll
        for (int k = 0; k < 4; ++k) gates[(size_t)r * 4 + k] = wv[k] * inv;
    }
}

// ---------------------------------------------------------------------------
// combined = sum_k gates[k]*experts[r,k,:]; x = LN(combined)*g+b + pe
// experts row layout: r*2048 + k*512 + d. One wave per row.
// ---------------------------------------------------------------------------
__global__ __launch_bounds__(64) void moe_ln_kernel(
    const float* __restrict__ experts, const float* __restrict__ gates,
    const float* __restrict__ g, const float* __restrict__ bb,
    const float* __restrict__ pe, float* __restrict__ x)
{
    const int r = blockIdx.x, t = threadIdx.x;
    const float* e = experts + (size_t)r * 2048;
    const float g0 = gates[r * 4 + 0], g1 = gates[r * 4 + 1];
    const float g2 = gates[r * 4 + 2], g3 = gates[r * 4 + 3];
    float v[8];
    #pragma unroll
    for (int it = 0; it < 8; ++it) {
        int d = t + it * 64;
        v[it] = g0 * e[d] + g1 * e[512 + d] + g2 * e[1024 + d] + g3 * e[1536 + d];
    }
    float s = 0.f;
    #pragma unroll
    for (int it = 0; it < 8; ++it) s += v[it];
    s = wave_sum(s);
    const float mu = s * (1.f / 512.f);
    float q = 0.f;
    #pragma unroll
    for (int it = 0; it < 8; ++it) { float dd = v[it] - mu; q += dd * dd; }
    q = wave_sum(q);
    const float rstd = rsqrtf(q * (1.f / 512.f) + 1e-5f);
    const float* per = pe + (size_t)(r & 1023) * 512;
    #pragma unroll
    for (int it = 0; it < 8; ++it) {
        int d = t + it * 64;
        x[(size_t)r * 512 + d] = (v[it] - mu) * rstd * g[d] + bb[d] + per[d];
    }
}

// x = LN(x + tbuf)*g + b  (one wave per row, in-place)
__global__ __launch_bounds__(64) void add_ln_kernel(
    float* __restrict__ x, const float* __restrict__ tbuf,
    const float* __restrict__ g, const float* __restrict__ bb)
{
    const int r = blockIdx.x, t = threadIdx.x;
    float* xr = x + (size_t)r * 512;
    const float* tr = tbuf + (size_t)r * 512;
    float v[8];
    #pragma unroll
    for (int it = 0; it < 8; ++it) { int d = t + it * 64; v[it] = xr[d] + tr[d]; }
    float s = 0.f;
    #pragma unroll
    for (int it = 0; it < 8; ++it) s += v[it];
    s = wave_sum(s);
    const float mu = s * (1.f / 512.f);
    float q = 0.f;
    #pragma unroll
    for (int it = 0; it < 8; ++it) { float dd = v[it] - mu; q += dd * dd; }
    q = wave_sum(q);
    const float rstd = rsqrtf(q * (1.f / 512.f) + 1e-5f);
    #pragma unroll
    for (int it = 0; it < 8; ++it) {
        int d = t + it * 64;
        xr[d] = (v[it] - mu) * rstd * g[d] + bb[d];
    }
}

// ---------------------------------------------------------------------------
// Strict-causal self-attention with Q=K=kh; row i=0 forced to zero ctx.
// One wave per (i, h, b). kh/vh/ctx layout: (b*S+s)*512 + h*64 + d.
// ---------------------------------------------------------------------------
__global__ __launch_bounds__(64) void attn_kernel(
    const float* __restrict__ kh, const float* __restrict__ vh,
    float* __restrict__ ctx)
{
    const int i = blockIdx.x, h = blockIdx.y, b = blockIdx.z;
    const int t = threadIdx.x;
    __shared__ float k0[64];
    __shared__ float sc[1024];

    const float* khb = kh + ((size_t)b * 1024) * 512 + h * 64;
    k0[t] = khb[(size_t)i * 512 + t];
    __syncthreads();

    float* crow = ctx + ((size_t)b * 1024 + i) * 512 + h * 64;
    if (i == 0) { crow[t] = 0.f; return; }

    float lmax = -INFINITY;
    for (int j = t; j < i; j += 64) {
        const float* kj = khb + (size_t)j * 512;
        float dot = 0.f;
        #pragma unroll
        for (int d = 0; d < 64; ++d) dot += k0[d] * kj[d];
        float sv = dot * 0.125f;
        sc[j] = sv;
        lmax = fmaxf(lmax, sv);
    }
    lmax = wave_max(lmax);
    float lsum = 0.f;
    for (int j = t; j < i; j += 64) {
        float e = __expf(sc[j] - lmax);
        sc[j] = e;
        lsum += e;
    }
    lsum = wave_sum(lsum);
    const float inv = 1.f / lsum;
    __syncthreads();

    float acc = 0.f;
    const float* vhb = vh + ((size_t)b * 1024) * 512 + h * 64 + t;
    for (int j = 0; j < i; ++j) acc += sc[j] * vhb[(size_t)j * 512];
    crow[t] = acc * inv;
}

__global__ void copy_kernel(const float* __restrict__ x, float* __restrict__ out)
{
    int idx = blockIdx.x * 256 + threadIdx.x;
    out[idx] = x[idx];
}

// ---------------------------------------------------------------------------
extern "C" void kernel_launch(void* const* d_in, const int* in_sizes, int n_in,
                              void* d_out, int out_size, void* d_ws, size_t ws_size,
                              hipStream_t stream)
{
    const float* q_raw   = (const float*)d_in[0];
    const float* m_seq   = (const float*)d_in[1];
    const float* qa      = (const float*)d_in[2];
    const float* exp_w1  = (const float*)d_in[3];
    const float* exp_b1  = (const float*)d_in[4];
    const float* exp_w2  = (const float*)d_in[5];
    const float* exp_b2  = (const float*)d_in[6];
    const float* adapt_w = (const float*)d_in[7];
    const float* adapt_b = (const float*)d_in[8];
    const float* gate_w  = (const float*)d_in[9];
    const float* gate_b  = (const float*)d_in[10];
    const float* moe_g   = (const float*)d_in[11];
    const float* moe_b   = (const float*)d_in[12];
    const float* kw      = (const float*)d_in[13];
    const float* kb      = (const float*)d_in[14];
    const float* vw      = (const float*)d_in[15];
    const float* vb      = (const float*)d_in[16];
    const float* ow      = (const float*)d_in[17];
    const float* ob      = (const float*)d_in[18];
    const float* ln1g    = (const float*)d_in[19];
    const float* ln1b    = (const float*)d_in[20];
    const float* fw1     = (const float*)d_in[21];
    const float* fb1     = (const float*)d_in[22];
    const float* fw2     = (const float*)d_in[23];
    const float* fb2     = (const float*)d_in[24];
    const float* ln2g    = (const float*)d_in[25];
    const float* ln2b    = (const float*)d_in[26];
    float* out = (float*)d_out;

    // workspace layout (floats); peak = 21,512,192 floats = 86.0 MB
    const size_t NEED = 21512192ull * 4ull;
    if (ws_size < NEED) return;   // clean no-op => absmax == max|ref| signature

    float* w = (float*)d_ws;
    float* pe    = w;                     //   524,288
    float* x     = pe + 524288;           // 2,097,152
    float* y     = x + 2097152;           // 2,097,152
    float* gates = y + 2097152;           //    16,384
    float* big   = gates + 16384;         // 16,777,216 (aliased)
    // phase-1 view
    float* h1      = big;                 // 3,145,728 (4096 x 768, one expert)
    float* experts = big + 3145728;       // 8,388,608 (4096 x 4 x 512)
    float* summary = big + 11534336;      // 2,097,152 (4096 x 512)
    // phase-2 view (phase-1 dead by then)
    float* kh  = big;                     // 2,097,152
    float* vh  = big + 2097152;           // 2,097,152
    float* ctx = big + 4194304;           // 2,097,152
    float* p   = big + 6291456;           // 2,097,152
    float* ffh = big + 8388608;           // 8,388,608 (4096 x 2048)

    pe_kernel<<<2048, 256, 0, stream>>>(pe);

    // ---- MoE phase (per-expert to bound h1) ----
    for (int k = 0; k < 4; ++k) {
        gemm_tile<<<dim3(12, 64), 256, 0, stream>>>(
            q_raw + k * 768, 3072, exp_w1 + (size_t)k * 589824, 768,
            exp_b1 + k * 768, h1, 768, 768, 1);
        gemm_tile<<<dim3(8, 64), 256, 0, stream>>>(
            h1, 768, exp_w2 + (size_t)k * 393216, 512,
            exp_b2 + k * 512, experts + k * 512, 2048, 768, 0);
    }
    gemm_tile<<<dim3(8, 64), 256, 0, stream>>>(
        q_raw, 3072, adapt_w, 512, adapt_b, summary, 512, 3072, 1);
    gate_kernel<<<4096, 64, 0, stream>>>(summary, m_seq, gate_w, gate_b, gates);
    moe_ln_kernel<<<4096, 64, 0, stream>>>(experts, gates, moe_g, moe_b, pe, x);
    y_kernel<<<8192, 256, 0, stream>>>(qa, pe, y);

    // ---- transformer layers ----
    for (int i = 0; i < 4; ++i) {
        gemm_tile<<<dim3(8, 64), 256, 0, stream>>>(
            x, 512, kw + (size_t)i * 262144, 512, kb + i * 512, kh, 512, 512, 0);
        gemm_tile<<<dim3(8, 64), 256, 0, stream>>>(
            y, 512, vw + (size_t)i * 262144, 512, vb + i * 512, vh, 512, 512, 0);
        attn_kernel<<<dim3(1024, 8, 4), 64, 0, stream>>>(kh, vh, ctx);
        gemm_tile<<<dim3(8, 64), 256, 0, stream>>>(
            ctx, 512, ow + (size_t)i * 262144, 512, ob + i * 512, p, 512, 512, 0);
        add_ln_kernel<<<4096, 64, 0, stream>>>(x, p, ln1g + i * 512, ln1b + i * 512);
        gemm_tile<<<dim3(32, 64), 256, 0, stream>>>(
            x, 512, fw1 + (size_t)i * 1048576, 2048, fb1 + i * 2048, ffh, 2048, 512, 1);
        gemm_tile<<<dim3(8, 64), 256, 0, stream>>>(
            ffh, 2048, fw2 + (size_t)i * 1048576, 512, fb2 + i * 512, p, 512, 2048, 0);
        add_ln_kernel<<<4096, 64, 0, stream>>>(x, p, ln2g + i * 512, ln2b + i * 512);
    }

    copy_kernel<<<8192, 256, 0, stream>>>(x, out);
}

// Round 3
// 2795.631 us; speedup vs baseline: 1.9192x; 1.9192x over previous
//
#include <hip/hip_runtime.h>
#include <hip/hip_bf16.h>

__device__ __forceinline__ float wave_sum(float v) {
    #pragma unroll
    for (int off = 32; off; off >>= 1) v += __shfl_xor(v, off);
    return v;
}

// ---------------------------------------------------------------------------
// Generic tiled GEMM: C[M,N] = act(A[M,K] @ B[K,N] + bias[N])
// All fp32. M,N multiples of 64; K multiple of 16; lda/ldb multiples of 4.
// 64x64 tile per 256-thread block, 4x4 per thread.
// ---------------------------------------------------------------------------
__global__ __launch_bounds__(256) void gemm_tile(
    const float* __restrict__ A, int lda,
    const float* __restrict__ Bm, int ldb,
    const float* __restrict__ bias,
    float* __restrict__ C, int ldc,
    int K, int act)
{
    __shared__ float As[16][68];  // A^T tile: [k][row], padded
    __shared__ float Bs[16][64];  // [k][col]

    const int tid = threadIdx.x;
    const int tx = tid & 15, ty = tid >> 4;
    const int rowBase = blockIdx.y * 64, colBase = blockIdx.x * 64;

    const int ar = tid >> 2;          // 0..63 : tile row
    const int ak = (tid & 3) << 2;    // 0,4,8,12 : k offset
    const int bk = tid >> 4;          // 0..15 : tile k row
    const int bc = (tid & 15) << 2;   // 0..60 : col offset

    float acc[4][4] = {};

    const float* aptr = A  + (size_t)(rowBase + ar) * lda + ak;
    const float* bptr = Bm + (size_t)bk * ldb + colBase + bc;

    for (int kt = 0; kt < K; kt += 16) {
        const float4 a4 = *(const float4*)aptr;
        const float4 b4 = *(const float4*)bptr;
        As[ak + 0][ar] = a4.x; As[ak + 1][ar] = a4.y; As[ak + 2][ar] = a4.z; As[ak + 3][ar] = a4.w;
        *(float4*)&Bs[bk][bc] = b4;
        __syncthreads();
        #pragma unroll
        for (int kk = 0; kk < 16; ++kk) {
            const float4 av = *(const float4*)&As[kk][ty << 2];
            const float4 bv = *(const float4*)&Bs[kk][tx << 2];
            acc[0][0] += av.x * bv.x; acc[0][1] += av.x * bv.y; acc[0][2] += av.x * bv.z; acc[0][3] += av.x * bv.w;
            acc[1][0] += av.y * bv.x; acc[1][1] += av.y * bv.y; acc[1][2] += av.y * bv.z; acc[1][3] += av.y * bv.w;
            acc[2][0] += av.z * bv.x; acc[2][1] += av.z * bv.y; acc[2][2] += av.z * bv.z; acc[2][3] += av.z * bv.w;
            acc[3][0] += av.w * bv.x; acc[3][1] += av.w * bv.y; acc[3][2] += av.w * bv.z; acc[3][3] += av.w * bv.w;
        }
        __syncthreads();
        aptr += 16;
        bptr += (size_t)16 * ldb;
    }

    #pragma unroll
    for (int rr = 0; rr < 4; ++rr) {
        const int row = rowBase + (ty << 2) + rr;
        float* crow = C + (size_t)row * ldc + colBase + (tx << 2);
        #pragma unroll
        for (int cc = 0; cc < 4; ++cc) {
            float v = acc[rr][cc] + bias[colBase + (tx << 2) + cc];
            if (act) v = fmaxf(v, 0.f);
            crow[cc] = v;
        }
    }
}

// ---------------------------------------------------------------------------
__global__ void pe_kernel(float* __restrict__ pe)
{
    int idx = blockIdx.x * 256 + threadIdx.x;   // 1024*512 total
    int s = idx >> 9, d = idx & 511;
    float div = expf((float)(d & ~1) * (-9.210340371976184f / 512.0f));
    float ang = (float)s * div;
    pe[idx] = (d & 1) ? cosf(ang) : sinf(ang);
}

__global__ void y_kernel(const float* __restrict__ qa, const float* __restrict__ pe,
                         float* __restrict__ y)
{
    int idx = blockIdx.x * 256 + threadIdx.x;   // 4096*512 total
    y[idx] = qa[idx] + pe[idx & 524287];
}

// ---------------------------------------------------------------------------
__global__ __launch_bounds__(64) void gate_kernel(
    const float* __restrict__ summary, const float* __restrict__ m_seq,
    const float* __restrict__ gw, const float* __restrict__ gb,
    float* __restrict__ gates)
{
    const int r = blockIdx.x, t = threadIdx.x;
    float p0 = 0.f, p1 = 0.f, p2 = 0.f, p3 = 0.f;
    const float* srow = summary + (size_t)r * 512;
    for (int j = t; j < 512; j += 64) {
        float s = srow[j];
        const float* g = gw + (size_t)j * 4;
        p0 += s * g[0]; p1 += s * g[1]; p2 += s * g[2]; p3 += s * g[3];
    }
    {
        float m = m_seq[(size_t)r * 64 + t];
        const float* g = gw + (size_t)(512 + t) * 4;
        p0 += m * g[0]; p1 += m * g[1]; p2 += m * g[2]; p3 += m * g[3];
    }
    p0 = wave_sum(p0); p1 = wave_sum(p1); p2 = wave_sum(p2); p3 = wave_sum(p3);
    if (t == 0) {
        float lg[4] = { p0 + gb[0], p1 + gb[1], p2 + gb[2], p3 + gb[3] };
        float m1 = -INFINITY, m2 = -INFINITY;
        #pragma unroll
        for (int k = 0; k < 4; ++k) {
            float v = lg[k];
            if (v > m1) { m2 = m1; m1 = v; }
            else if (v > m2) { m2 = v; }
        }
        float wv[4], s = 0.f;
        #pragma unroll
        for (int k = 0; k < 4; ++k) {
            wv[k] = (lg[k] >= m2) ? __expf(lg[k] - m1) : 0.f;
            s += wv[k];
        }
        float inv = 1.f / s;
        #pragma unroll
        for (int k = 0; k < 4; ++k) gates[(size_t)r * 4 + k] = wv[k] * inv;
    }
}

// ---------------------------------------------------------------------------
__global__ __launch_bounds__(64) void moe_ln_kernel(
    const float* __restrict__ experts, const float* __restrict__ gates,
    const float* __restrict__ g, const float* __restrict__ bb,
    const float* __restrict__ pe, float* __restrict__ x)
{
    const int r = blockIdx.x, t = threadIdx.x;
    const float* e = experts + (size_t)r * 2048;
    const float g0 = gates[r * 4 + 0], g1 = gates[r * 4 + 1];
    const float g2 = gates[r * 4 + 2], g3 = gates[r * 4 + 3];
    float v[8];
    #pragma unroll
    for (int it = 0; it < 8; ++it) {
        int d = t + it * 64;
        v[it] = g0 * e[d] + g1 * e[512 + d] + g2 * e[1024 + d] + g3 * e[1536 + d];
    }
    float s = 0.f;
    #pragma unroll
    for (int it = 0; it < 8; ++it) s += v[it];
    s = wave_sum(s);
    const float mu = s * (1.f / 512.f);
    float q = 0.f;
    #pragma unroll
    for (int it = 0; it < 8; ++it) { float dd = v[it] - mu; q += dd * dd; }
    q = wave_sum(q);
    const float rstd = rsqrtf(q * (1.f / 512.f) + 1e-5f);
    const float* per = pe + (size_t)(r & 1023) * 512;
    #pragma unroll
    for (int it = 0; it < 8; ++it) {
        int d = t + it * 64;
        x[(size_t)r * 512 + d] = (v[it] - mu) * rstd * g[d] + bb[d] + per[d];
    }
}

__global__ __launch_bounds__(64) void add_ln_kernel(
    float* __restrict__ x, const float* __restrict__ tbuf,
    const float* __restrict__ g, const float* __restrict__ bb)
{
    const int r = blockIdx.x, t = threadIdx.x;
    float* xr = x + (size_t)r * 512;
    const float* tr = tbuf + (size_t)r * 512;
    float v[8];
    #pragma unroll
    for (int it = 0; it < 8; ++it) { int d = t + it * 64; v[it] = xr[d] + tr[d]; }
    float s = 0.f;
    #pragma unroll
    for (int it = 0; it < 8; ++it) s += v[it];
    s = wave_sum(s);
    const float mu = s * (1.f / 512.f);
    float q = 0.f;
    #pragma unroll
    for (int it = 0; it < 8; ++it) { float dd = v[it] - mu; q += dd * dd; }
    q = wave_sum(q);
    const float rstd = rsqrtf(q * (1.f / 512.f) + 1e-5f);
    #pragma unroll
    for (int it = 0; it < 8; ++it) {
        int d = t + it * 64;
        xr[d] = (v[it] - mu) * rstd * g[d] + bb[d];
    }
}

// ---------------------------------------------------------------------------
// Flash-style strict-causal attention, Q=K=kh, V=vh.
// Block = 256 threads handles one 64-row Q tile for one (b,h).
// grid = (B=4, H=8, 16 z-slots); z->it mapping pairs (it, 15-it) across the
// two 256-block dispatch sweeps for load balance (17 tile-units per CU).
// LDS: Qt[d][row] 16KB, KV 17KB (K-transposed phase then V phase), Pt 17KB.
// 4x4 per-thread register tiles for both QK^T and PV; online softmax in
// registers with 16-lane shuffle reductions (row == 16 contiguous lanes).
// Row i=0 fully masked -> l==0 -> output 0 (matches attn[:,:,0,:]=0).
// ---------------------------------------------------------------------------
__global__ __launch_bounds__(256) void attn_kernel(
    const float* __restrict__ kh, const float* __restrict__ vh,
    float* __restrict__ ctx)
{
    __shared__ float Qt[64][64];   // [d][row]
    __shared__ float KV[64][68];   // K: [d][j] ; V: [j][d]  (barrier-separated)
    __shared__ float Pt[64][68];   // [j][row]

    const int tid = threadIdx.x;
    const int tx = tid & 15, ty = tid >> 4;
    const int b = blockIdx.x, h = blockIdx.y;
    const int bz = blockIdx.z;
    const int it = (bz < 8) ? bz : (23 - bz);

    const float* khb = kh + ((size_t)b * 1024) * 512 + h * 64;
    const float* vhb = vh + ((size_t)b * 1024) * 512 + h * 64;

    const int lj = tid >> 2;   // 0..63 : source row
    const int lc = tid & 3;    // 0..3  : float4 chunk group

    // ---- load Q tile transposed: Qt[d][row] ----
    {
        const float* qsrc = khb + (size_t)(it * 64 + lj) * 512;
        #pragma unroll
        for (int k = 0; k < 4; ++k) {
            const int d0 = (lc + 4 * k) * 4;
            float4 q4 = *(const float4*)(qsrc + d0);
            Qt[d0 + 0][lj] = q4.x; Qt[d0 + 1][lj] = q4.y;
            Qt[d0 + 2][lj] = q4.z; Qt[d0 + 3][lj] = q4.w;
        }
    }

    float o_acc[4][4] = {};
    float m_run[4] = { -INFINITY, -INFINITY, -INFINITY, -INFINITY };
    float l_run[4] = {};

    __syncthreads();

    for (int jt = 0; jt <= it; ++jt) {
        // prefetch V tile into registers (consumed after QK)
        const float* vsrc = vhb + (size_t)(jt * 64 + lj) * 512;
        float4 vreg[4];
        #pragma unroll
        for (int k = 0; k < 4; ++k) vreg[k] = *(const float4*)(vsrc + (lc + 4 * k) * 4);

        // load K tile transposed: KV[d][j]
        const float* ksrc = khb + (size_t)(jt * 64 + lj) * 512;
        #pragma unroll
        for (int k = 0; k < 4; ++k) {
            const int d0 = (lc + 4 * k) * 4;
            float4 k4 = *(const float4*)(ksrc + d0);
            KV[d0 + 0][lj] = k4.x; KV[d0 + 1][lj] = k4.y;
            KV[d0 + 2][lj] = k4.z; KV[d0 + 3][lj] = k4.w;
        }
        __syncthreads();

        // ---- QK^T: acc[rr][cc] = sum_d Q[row][d] * K[j][d] ----
        float acc[4][4] = {};
        #pragma unroll 8
        for (int d = 0; d < 64; ++d) {
            const float4 av = *(const float4*)&Qt[d][ty << 2];
            const float4 bv = *(const float4*)&KV[d][tx << 2];
            acc[0][0] += av.x * bv.x; acc[0][1] += av.x * bv.y; acc[0][2] += av.x * bv.z; acc[0][3] += av.x * bv.w;
            acc[1][0] += av.y * bv.x; acc[1][1] += av.y * bv.y; acc[1][2] += av.y * bv.z; acc[1][3] += av.y * bv.w;
            acc[2][0] += av.z * bv.x; acc[2][1] += av.z * bv.y; acc[2][2] += av.z * bv.z; acc[2][3] += av.z * bv.w;
            acc[3][0] += av.w * bv.x; acc[3][1] += av.w * bv.y; acc[3][2] += av.w * bv.z; acc[3][3] += av.w * bv.w;
        }
        __syncthreads();   // all waves done reading KV as K

        // store V tile: KV[j][d]
        #pragma unroll
        for (int k = 0; k < 4; ++k) *(float4*)&KV[lj][(lc + 4 * k) * 4] = vreg[k];

        // ---- scale + strict-causal mask (diagonal tile only) ----
        const bool diag = (jt == it);
        #pragma unroll
        for (int rr = 0; rr < 4; ++rr) {
            #pragma unroll
            for (int cc = 0; cc < 4; ++cc) {
                float sv = acc[rr][cc] * 0.125f;
                if (diag && ((tx << 2) + cc) >= ((ty << 2) + rr)) sv = -INFINITY;
                acc[rr][cc] = sv;
            }
        }

        // ---- online softmax (row = 16 contiguous lanes) ----
        #pragma unroll
        for (int rr = 0; rr < 4; ++rr) {
            float mb = fmaxf(fmaxf(acc[rr][0], acc[rr][1]), fmaxf(acc[rr][2], acc[rr][3]));
            #pragma unroll
            for (int off = 1; off < 16; off <<= 1) mb = fmaxf(mb, __shfl_xor(mb, off));
            const float mn = fmaxf(m_run[rr], mb);
            const float mfix = (mn == -INFINITY) ? 0.f : mn;
            const float alpha = (m_run[rr] == -INFINITY) ? 0.f : __expf(m_run[rr] - mn);
            m_run[rr] = mn;
            const float p0 = __expf(acc[rr][0] - mfix);
            const float p1 = __expf(acc[rr][1] - mfix);
            const float p2 = __expf(acc[rr][2] - mfix);
            const float p3 = __expf(acc[rr][3] - mfix);
            float rs = p0 + p1 + p2 + p3;
            #pragma unroll
            for (int off = 1; off < 16; off <<= 1) rs += __shfl_xor(rs, off);
            l_run[rr] = l_run[rr] * alpha + rs;
            const int row = (ty << 2) + rr;
            Pt[(tx << 2) + 0][row] = p0;
            Pt[(tx << 2) + 1][row] = p1;
            Pt[(tx << 2) + 2][row] = p2;
            Pt[(tx << 2) + 3][row] = p3;
            o_acc[rr][0] *= alpha; o_acc[rr][1] *= alpha;
            o_acc[rr][2] *= alpha; o_acc[rr][3] *= alpha;
        }
        __syncthreads();   // V and Pt ready

        // ---- PV: o_acc[rr][cc] += sum_j P[row][j] * V[j][d] ----
        #pragma unroll 8
        for (int j = 0; j < 64; ++j) {
            const float4 av = *(const float4*)&Pt[j][ty << 2];
            const float4 bv = *(const float4*)&KV[j][tx << 2];
            o_acc[0][0] += av.x * bv.x; o_acc[0][1] += av.x * bv.y; o_acc[0][2] += av.x * bv.z; o_acc[0][3] += av.x * bv.w;
            o_acc[1][0] += av.y * bv.x; o_acc[1][1] += av.y * bv.y; o_acc[1][2] += av.y * bv.z; o_acc[1][3] += av.y * bv.w;
            o_acc[2][0] += av.z * bv.x; o_acc[2][1] += av.z * bv.y; o_acc[2][2] += av.z * bv.z; o_acc[2][3] += av.z * bv.w;
            o_acc[3][0] += av.w * bv.x; o_acc[3][1] += av.w * bv.y; o_acc[3][2] += av.w * bv.z; o_acc[3][3] += av.w * bv.w;
        }
        __syncthreads();   // done with KV/Pt before next tile's loads
    }

    // ---- normalize + write ctx ----
    float* ctxb = ctx + ((size_t)b * 1024 + (size_t)it * 64) * 512 + h * 64;
    #pragma unroll
    for (int rr = 0; rr < 4; ++rr) {
        const int row = (ty << 2) + rr;
        const float inv = (l_run[rr] > 0.f) ? 1.f / l_run[rr] : 0.f;
        float4 o;
        o.x = o_acc[rr][0] * inv; o.y = o_acc[rr][1] * inv;
        o.z = o_acc[rr][2] * inv; o.w = o_acc[rr][3] * inv;
        *(float4*)(ctxb + (size_t)row * 512 + (tx << 2)) = o;
    }
}

__global__ void copy_kernel(const float* __restrict__ x, float* __restrict__ out)
{
    int idx = blockIdx.x * 256 + threadIdx.x;
    out[idx] = x[idx];
}

// ---------------------------------------------------------------------------
extern "C" void kernel_launch(void* const* d_in, const int* in_sizes, int n_in,
                              void* d_out, int out_size, void* d_ws, size_t ws_size,
                              hipStream_t stream)
{
    const float* q_raw   = (const float*)d_in[0];
    const float* m_seq   = (const float*)d_in[1];
    const float* qa      = (const float*)d_in[2];
    const float* exp_w1  = (const float*)d_in[3];
    const float* exp_b1  = (const float*)d_in[4];
    const float* exp_w2  = (const float*)d_in[5];
    const float* exp_b2  = (const float*)d_in[6];
    const float* adapt_w = (const float*)d_in[7];
    const float* adapt_b = (const float*)d_in[8];
    const float* gate_w  = (const float*)d_in[9];
    const float* gate_b  = (const float*)d_in[10];
    const float* moe_g   = (const float*)d_in[11];
    const float* moe_b   = (const float*)d_in[12];
    const float* kw      = (const float*)d_in[13];
    const float* kb      = (const float*)d_in[14];
    const float* vw      = (const float*)d_in[15];
    const float* vb      = (const float*)d_in[16];
    const float* ow      = (const float*)d_in[17];
    const float* ob      = (const float*)d_in[18];
    const float* ln1g    = (const float*)d_in[19];
    const float* ln1b    = (const float*)d_in[20];
    const float* fw1     = (const float*)d_in[21];
    const float* fb1     = (const float*)d_in[22];
    const float* fw2     = (const float*)d_in[23];
    const float* fb2     = (const float*)d_in[24];
    const float* ln2g    = (const float*)d_in[25];
    const float* ln2b    = (const float*)d_in[26];
    float* out = (float*)d_out;

    // workspace layout (floats); peak = 21,512,192 floats = 86.0 MB
    const size_t NEED = 21512192ull * 4ull;
    if (ws_size < NEED) return;

    float* w = (float*)d_ws;
    float* pe    = w;                     //   524,288
    float* x     = pe + 524288;           // 2,097,152
    float* y     = x + 2097152;           // 2,097,152
    float* gates = y + 2097152;           //    16,384
    float* big   = gates + 16384;         // 16,777,216 (aliased)
    // phase-1 view
    float* h1      = big;                 // 3,145,728 (4096 x 768, one expert)
    float* experts = big + 3145728;       // 8,388,608 (4096 x 4 x 512)
    float* summary = big + 11534336;      // 2,097,152 (4096 x 512)
    // phase-2 view
    float* kh  = big;                     // 2,097,152
    float* vh  = big + 2097152;           // 2,097,152
    float* ctx = big + 4194304;           // 2,097,152
    float* p   = big + 6291456;           // 2,097,152
    float* ffh = big + 8388608;           // 8,388,608 (4096 x 2048)

    pe_kernel<<<2048, 256, 0, stream>>>(pe);

    // ---- MoE phase ----
    for (int k = 0; k < 4; ++k) {
        gemm_tile<<<dim3(12, 64), 256, 0, stream>>>(
            q_raw + k * 768, 3072, exp_w1 + (size_t)k * 589824, 768,
            exp_b1 + k * 768, h1, 768, 768, 1);
        gemm_tile<<<dim3(8, 64), 256, 0, stream>>>(
            h1, 768, exp_w2 + (size_t)k * 393216, 512,
            exp_b2 + k * 512, experts + k * 512, 2048, 768, 0);
    }
    gemm_tile<<<dim3(8, 64), 256, 0, stream>>>(
        q_raw, 3072, adapt_w, 512, adapt_b, summary, 512, 3072, 1);
    gate_kernel<<<4096, 64, 0, stream>>>(summary, m_seq, gate_w, gate_b, gates);
    moe_ln_kernel<<<4096, 64, 0, stream>>>(experts, gates, moe_g, moe_b, pe, x);
    y_kernel<<<8192, 256, 0, stream>>>(qa, pe, y);

    // ---- transformer layers ----
    for (int i = 0; i < 4; ++i) {
        gemm_tile<<<dim3(8, 64), 256, 0, stream>>>(
            x, 512, kw + (size_t)i * 262144, 512, kb + i * 512, kh, 512, 512, 0);
        gemm_tile<<<dim3(8, 64), 256, 0, stream>>>(
            y, 512, vw + (size_t)i * 262144, 512, vb + i * 512, vh, 512, 512, 0);
        attn_kernel<<<dim3(4, 8, 16), 256, 0, stream>>>(kh, vh, ctx);
        gemm_tile<<<dim3(8, 64), 256, 0, stream>>>(
            ctx, 512, ow + (size_t)i * 262144, 512, ob + i * 512, p, 512, 512, 0);
        add_ln_kernel<<<4096, 64, 0, stream>>>(x, p, ln1g + i * 512, ln1b + i * 512);
        gemm_tile<<<dim3(32, 64), 256, 0, stream>>>(
            x, 512, fw1 + (size_t)i * 1048576, 2048, fb1 + i * 2048, ffh, 2048, 512, 1);
        gemm_tile<<<dim3(8, 64), 256, 0, stream>>>(
            ffh, 2048, fw2 + (size_t)i * 1048576, 512, fb2 + i * 512, p, 512, 2048, 0);
        add_ln_kernel<<<4096, 64, 0, stream>>>(x, p, ln2g + i * 512, ln2b + i * 512);
    }

    copy_kernel<<<8192, 256, 0, stream>>>(x, out);
}

// Round 6
// 1523.448 us; speedup vs baseline: 3.5219x; 1.8351x over previous
//
#include <hip/hip_runtime.h>
#include <hip/hip_bf16.h>

typedef unsigned short u16;
typedef __attribute__((ext_vector_type(8))) short short8;
typedef __attribute__((ext_vector_type(4))) float floatx4;

__device__ __forceinline__ float bf2f(u16 u) {
    unsigned x = (unsigned)u << 16;
    return __uint_as_float(x);
}
__device__ __forceinline__ u16 f2bf(float f) {   // round-to-nearest-even
    unsigned x = __float_as_uint(f);
    unsigned r = (x + 0x7fffu + ((x >> 16) & 1u)) >> 16;
    return (u16)r;
}

__device__ __forceinline__ float wave_sum(float v) {
    #pragma unroll
    for (int off = 32; off; off >>= 1) v += __shfl_xor(v, off);
    return v;
}

// ---------------------------------------------------------------------------
// bf16 MFMA GEMM: C[M,N] = act(A[M,K] @ B[K,N] + bias[N]), Bt = B^T [N][K].
// 128x128 tile / 256 threads / 4 waves; fp32 accumulate.
// C/D mapping col=lane&15,row=quad*4+reg (runtime-probe-confirmed in R5).
// ---------------------------------------------------------------------------
__global__ __launch_bounds__(256) void gemm_bf16(
    const u16* __restrict__ A, int lda,
    const u16* __restrict__ Bt, int ldb,
    const float* __restrict__ bias,
    float* __restrict__ Cf, u16* __restrict__ Cb, int ldc,
    int K, int act)
{
    __shared__ __align__(16) u16 Asm[128 * 32];
    __shared__ __align__(16) u16 Bsm[128 * 32];

    const int tid = threadIdx.x;
    const int lane = tid & 63;
    const int wave = tid >> 6;
    const int m0 = blockIdx.y * 128, n0 = blockIdx.x * 128;
    const int wm = (wave >> 1) * 64, wn = (wave & 1) * 64;

    const int r0 = tid >> 2;
    const int kc = (tid & 3) * 8;

    const int kq = (lane >> 4) * 8;
    const int fm = lane & 15;

    const floatx4 zz = {0.f, 0.f, 0.f, 0.f};
    floatx4 acc[4][4];
    #pragma unroll
    for (int mt = 0; mt < 4; ++mt)
        #pragma unroll
        for (int nt = 0; nt < 4; ++nt) acc[mt][nt] = zz;

    for (int kt = 0; kt < K; kt += 32) {
        *(uint4*)&Asm[r0 * 32 + kc]        = *(const uint4*)&A[(size_t)(m0 + r0) * lda + kt + kc];
        *(uint4*)&Asm[(r0 + 64) * 32 + kc] = *(const uint4*)&A[(size_t)(m0 + r0 + 64) * lda + kt + kc];
        *(uint4*)&Bsm[r0 * 32 + kc]        = *(const uint4*)&Bt[(size_t)(n0 + r0) * ldb + kt + kc];
        *(uint4*)&Bsm[(r0 + 64) * 32 + kc] = *(const uint4*)&Bt[(size_t)(n0 + r0 + 64) * ldb + kt + kc];
        __syncthreads();

        short8 af[4], bfr[4];
        #pragma unroll
        for (int mt = 0; mt < 4; ++mt)
            af[mt] = *(const short8*)&Asm[(wm + mt * 16 + fm) * 32 + kq];
        #pragma unroll
        for (int nt = 0; nt < 4; ++nt)
            bfr[nt] = *(const short8*)&Bsm[(wn + nt * 16 + fm) * 32 + kq];

        #pragma unroll
        for (int mt = 0; mt < 4; ++mt)
            #pragma unroll
            for (int nt = 0; nt < 4; ++nt)
                acc[mt][nt] = __builtin_amdgcn_mfma_f32_16x16x32_bf16(
                    af[mt], bfr[nt], acc[mt][nt], 0, 0, 0);
        __syncthreads();
    }

    const int cr = (lane >> 4) * 4;
    #pragma unroll
    for (int mt = 0; mt < 4; ++mt) {
        #pragma unroll
        for (int nt = 0; nt < 4; ++nt) {
            const int col = n0 + wn + nt * 16 + fm;
            const float bz = bias[col];
            #pragma unroll
            for (int r = 0; r < 4; ++r) {
                const int row = m0 + wm + mt * 16 + cr + r;
                float v = acc[mt][nt][r] + bz;
                if (act) v = fmaxf(v, 0.f);
                if (Cf) Cf[(size_t)row * ldc + col] = v;
                if (Cb) Cb[(size_t)row * ldc + col] = f2bf(v);
            }
        }
    }
}

// ---------------------------------------------------------------------------
// fp32 VALU GEMM (round-3 verified): C = act(A@B + bias). Used ONLY for the
// gate-determining adapter GEMM: top-2 selection is discontinuous, so the
// logit path must match the np reference's fp32 numerics, not bf16.
// ---------------------------------------------------------------------------
__global__ __launch_bounds__(256) void gemm_tile(
    const float* __restrict__ A, int lda,
    const float* __restrict__ Bm, int ldb,
    const float* __restrict__ bias,
    float* __restrict__ C, int ldc,
    int K, int act)
{
    __shared__ float As[16][68];
    __shared__ float Bs[16][64];

    const int tid = threadIdx.x;
    const int tx = tid & 15, ty = tid >> 4;
    const int rowBase = blockIdx.y * 64, colBase = blockIdx.x * 64;

    const int ar = tid >> 2;
    const int ak = (tid & 3) << 2;
    const int bk = tid >> 4;
    const int bc = (tid & 15) << 2;

    float acc[4][4] = {};

    const float* aptr = A  + (size_t)(rowBase + ar) * lda + ak;
    const float* bptr = Bm + (size_t)bk * ldb + colBase + bc;

    for (int kt = 0; kt < K; kt += 16) {
        const float4 a4 = *(const float4*)aptr;
        const float4 b4 = *(const float4*)bptr;
        As[ak + 0][ar] = a4.x; As[ak + 1][ar] = a4.y; As[ak + 2][ar] = a4.z; As[ak + 3][ar] = a4.w;
        *(float4*)&Bs[bk][bc] = b4;
        __syncthreads();
        #pragma unroll
        for (int kk = 0; kk < 16; ++kk) {
            const float4 av = *(const float4*)&As[kk][ty << 2];
            const float4 bv = *(const float4*)&Bs[kk][tx << 2];
            acc[0][0] += av.x * bv.x; acc[0][1] += av.x * bv.y; acc[0][2] += av.x * bv.z; acc[0][3] += av.x * bv.w;
            acc[1][0] += av.y * bv.x; acc[1][1] += av.y * bv.y; acc[1][2] += av.y * bv.z; acc[1][3] += av.y * bv.w;
            acc[2][0] += av.z * bv.x; acc[2][1] += av.z * bv.y; acc[2][2] += av.z * bv.z; acc[2][3] += av.z * bv.w;
            acc[3][0] += av.w * bv.x; acc[3][1] += av.w * bv.y; acc[3][2] += av.w * bv.z; acc[3][3] += av.w * bv.w;
        }
        __syncthreads();
        aptr += 16;
        bptr += (size_t)16 * ldb;
    }

    #pragma unroll
    for (int rr = 0; rr < 4; ++rr) {
        const int row = rowBase + (ty << 2) + rr;
        float* crow = C + (size_t)row * ldc + colBase + (tx << 2);
        #pragma unroll
        for (int cc = 0; cc < 4; ++cc) {
            float v = acc[rr][cc] + bias[colBase + (tx << 2) + cc];
            if (act) v = fmaxf(v, 0.f);
            crow[cc] = v;
        }
    }
}

// ---------------------------------------------------------------------------
// fp32 [K][N] -> bf16 [N][K] (transposed), batched. 32x32 tiles, 256 threads.
// ---------------------------------------------------------------------------
__global__ __launch_bounds__(256) void tconv_kernel(
    const float* __restrict__ in, u16* __restrict__ out, int K, int N)
{
    __shared__ float t[32][33];
    const int n0 = blockIdx.x * 32, k0 = blockIdx.y * 32;
    const size_t bo = (size_t)blockIdx.z * K * N;
    const int tx = threadIdx.x & 31, ty = threadIdx.x >> 5;
    const float* src = in + bo;
    u16* dst = out + bo;
    #pragma unroll
    for (int r = ty; r < 32; r += 8) t[r][tx] = src[(size_t)(k0 + r) * N + n0 + tx];
    __syncthreads();
    #pragma unroll
    for (int r = ty; r < 32; r += 8) dst[(size_t)(n0 + r) * K + k0 + tx] = f2bf(t[tx][r]);
}

__global__ void f2b_kernel(const float* __restrict__ in, u16* __restrict__ out, int n)
{
    int i = blockIdx.x * 256 + threadIdx.x;
    if (i < n) out[i] = f2bf(in[i]);
}

// ---------------------------------------------------------------------------
__global__ void pe_kernel(float* __restrict__ pe)
{
    int idx = blockIdx.x * 256 + threadIdx.x;
    int s = idx >> 9, d = idx & 511;
    float div = expf((float)(d & ~1) * (-9.210340371976184f / 512.0f));
    float ang = (float)s * div;
    pe[idx] = (d & 1) ? cosf(ang) : sinf(ang);
}

__global__ void y_kernel(const float* __restrict__ qa, const float* __restrict__ pe,
                         u16* __restrict__ yb)
{
    int idx = blockIdx.x * 256 + threadIdx.x;
    yb[idx] = f2bf(qa[idx] + pe[idx & 524287]);
}

// ---------------------------------------------------------------------------
__global__ __launch_bounds__(64) void gate_kernel(
    const float* __restrict__ summary, const float* __restrict__ m_seq,
    const float* __restrict__ gw, const float* __restrict__ gb,
    float* __restrict__ gates)
{
    const int r = blockIdx.x, t = threadIdx.x;
    float p0 = 0.f, p1 = 0.f, p2 = 0.f, p3 = 0.f;
    const float* srow = summary + (size_t)r * 512;
    for (int j = t; j < 512; j += 64) {
        float s = srow[j];
        const float* g = gw + (size_t)j * 4;
        p0 += s * g[0]; p1 += s * g[1]; p2 += s * g[2]; p3 += s * g[3];
    }
    {
        float m = m_seq[(size_t)r * 64 + t];
        const float* g = gw + (size_t)(512 + t) * 4;
        p0 += m * g[0]; p1 += m * g[1]; p2 += m * g[2]; p3 += m * g[3];
    }
    p0 = wave_sum(p0); p1 = wave_sum(p1); p2 = wave_sum(p2); p3 = wave_sum(p3);
    if (t == 0) {
        float lg[4] = { p0 + gb[0], p1 + gb[1], p2 + gb[2], p3 + gb[3] };
        float m1 = -INFINITY, m2 = -INFINITY;
        #pragma unroll
        for (int k = 0; k < 4; ++k) {
            float v = lg[k];
            if (v > m1) { m2 = m1; m1 = v; }
            else if (v > m2) { m2 = v; }
        }
        float wv[4], s = 0.f;
        #pragma unroll
        for (int k = 0; k < 4; ++k) {
            wv[k] = (lg[k] >= m2) ? __expf(lg[k] - m1) : 0.f;
            s += wv[k];
        }
        float inv = 1.f / s;
        #pragma unroll
        for (int k = 0; k < 4; ++k) gates[(size_t)r * 4 + k] = wv[k] * inv;
    }
}

// ---------------------------------------------------------------------------
__global__ __launch_bounds__(64) void moe_ln_kernel(
    const u16* __restrict__ experts, const float* __restrict__ gates,
    const float* __restrict__ g, const float* __restrict__ bb,
    const float* __restrict__ pe, float* __restrict__ x, u16* __restrict__ xb)
{
    const int r = blockIdx.x, t = threadIdx.x;
    const u16* e = experts + (size_t)r * 2048;
    const float g0 = gates[r * 4 + 0], g1 = gates[r * 4 + 1];
    const float g2 = gates[r * 4 + 2], g3 = gates[r * 4 + 3];
    float v[8];
    #pragma unroll
    for (int it = 0; it < 8; ++it) {
        int d = t + it * 64;
        v[it] = g0 * bf2f(e[d]) + g1 * bf2f(e[512 + d])
              + g2 * bf2f(e[1024 + d]) + g3 * bf2f(e[1536 + d]);
    }
    float s = 0.f;
    #pragma unroll
    for (int it = 0; it < 8; ++it) s += v[it];
    s = wave_sum(s);
    const float mu = s * (1.f / 512.f);
    float q = 0.f;
    #pragma unroll
    for (int it = 0; it < 8; ++it) { float dd = v[it] - mu; q += dd * dd; }
    q = wave_sum(q);
    const float rstd = rsqrtf(q * (1.f / 512.f) + 1e-5f);
    const float* per = pe + (size_t)(r & 1023) * 512;
    #pragma unroll
    for (int it = 0; it < 8; ++it) {
        int d = t + it * 64;
        float o = (v[it] - mu) * rstd * g[d] + bb[d] + per[d];
        x[(size_t)r * 512 + d] = o;
        xb[(size_t)r * 512 + d] = f2bf(o);
    }
}

__global__ __launch_bounds__(64) void add_ln_kernel(
    float* __restrict__ x, u16* __restrict__ xb, const float* __restrict__ tbuf,
    const float* __restrict__ g, const float* __restrict__ bb)
{
    const int r = blockIdx.x, t = threadIdx.x;
    float* xr = x + (size_t)r * 512;
    const float* tr = tbuf + (size_t)r * 512;
    float v[8];
    #pragma unroll
    for (int it = 0; it < 8; ++it) { int d = t + it * 64; v[it] = xr[d] + tr[d]; }
    float s = 0.f;
    #pragma unroll
    for (int it = 0; it < 8; ++it) s += v[it];
    s = wave_sum(s);
    const float mu = s * (1.f / 512.f);
    float q = 0.f;
    #pragma unroll
    for (int it = 0; it < 8; ++it) { float dd = v[it] - mu; q += dd * dd; }
    q = wave_sum(q);
    const float rstd = rsqrtf(q * (1.f / 512.f) + 1e-5f);
    #pragma unroll
    for (int it = 0; it < 8; ++it) {
        int d = t + it * 64;
        float o = (v[it] - mu) * rstd * g[d] + bb[d];
        xr[d] = o;
        xb[(size_t)r * 512 + d] = f2bf(o);
    }
}

// ---------------------------------------------------------------------------
// Flash strict-causal attention; Q=K=khb (bf16), V=vhb (bf16), ctx -> bf16.
// ---------------------------------------------------------------------------
__global__ __launch_bounds__(256) void attn_kernel(
    const u16* __restrict__ kh, const u16* __restrict__ vh,
    u16* __restrict__ ctx)
{
    __shared__ float Qt[64][64];
    __shared__ float KV[64][68];
    __shared__ float Pt[64][68];

    const int tid = threadIdx.x;
    const int tx = tid & 15, ty = tid >> 4;
    const int b = blockIdx.x, h = blockIdx.y;
    const int bz = blockIdx.z;
    const int it = (bz < 8) ? bz : (23 - bz);

    const u16* khb = kh + ((size_t)b * 1024) * 512 + h * 64;
    const u16* vhb = vh + ((size_t)b * 1024) * 512 + h * 64;

    const int lj = tid >> 2;
    const int lc = tid & 3;

    {
        const u16* qsrc = khb + (size_t)(it * 64 + lj) * 512 + lc * 16;
        uint4 u0 = *(const uint4*)qsrc;
        uint4 u1 = *(const uint4*)(qsrc + 8);
        const u16* us0 = (const u16*)&u0;
        const u16* us1 = (const u16*)&u1;
        #pragma unroll
        for (int e = 0; e < 8; ++e) Qt[lc * 16 + e][lj] = bf2f(us0[e]);
        #pragma unroll
        for (int e = 0; e < 8; ++e) Qt[lc * 16 + 8 + e][lj] = bf2f(us1[e]);
    }

    float o_acc[4][4] = {};
    float m_run[4] = { -INFINITY, -INFINITY, -INFINITY, -INFINITY };
    float l_run[4] = {};

    __syncthreads();

    for (int jt = 0; jt <= it; ++jt) {
        const u16* vsrc = vhb + (size_t)(jt * 64 + lj) * 512 + lc * 16;
        uint4 v0 = *(const uint4*)vsrc;
        uint4 v1 = *(const uint4*)(vsrc + 8);

        const u16* ksrc = khb + (size_t)(jt * 64 + lj) * 512 + lc * 16;
        uint4 k0 = *(const uint4*)ksrc;
        uint4 k1 = *(const uint4*)(ksrc + 8);
        {
            const u16* us0 = (const u16*)&k0;
            const u16* us1 = (const u16*)&k1;
            #pragma unroll
            for (int e = 0; e < 8; ++e) KV[lc * 16 + e][lj] = bf2f(us0[e]);
            #pragma unroll
            for (int e = 0; e < 8; ++e) KV[lc * 16 + 8 + e][lj] = bf2f(us1[e]);
        }
        __syncthreads();

        float acc[4][4] = {};
        #pragma unroll 8
        for (int d = 0; d < 64; ++d) {
            const float4 av = *(const float4*)&Qt[d][ty << 2];
            const float4 bv = *(const float4*)&KV[d][tx << 2];
            acc[0][0] += av.x * bv.x; acc[0][1] += av.x * bv.y; acc[0][2] += av.x * bv.z; acc[0][3] += av.x * bv.w;
            acc[1][0] += av.y * bv.x; acc[1][1] += av.y * bv.y; acc[1][2] += av.y * bv.z; acc[1][3] += av.y * bv.w;
            acc[2][0] += av.z * bv.x; acc[2][1] += av.z * bv.y; acc[2][2] += av.z * bv.z; acc[2][3] += av.z * bv.w;
            acc[3][0] += av.w * bv.x; acc[3][1] += av.w * bv.y; acc[3][2] += av.w * bv.z; acc[3][3] += av.w * bv.w;
        }
        __syncthreads();

        {
            const u16* us0 = (const u16*)&v0;
            const u16* us1 = (const u16*)&v1;
            #pragma unroll
            for (int e = 0; e < 8; ++e) KV[lj][lc * 16 + e] = bf2f(us0[e]);
            #pragma unroll
            for (int e = 0; e < 8; ++e) KV[lj][lc * 16 + 8 + e] = bf2f(us1[e]);
        }

        const bool diag = (jt == it);
        #pragma unroll
        for (int rr = 0; rr < 4; ++rr)
            #pragma unroll
            for (int cc = 0; cc < 4; ++cc) {
                float sv = acc[rr][cc] * 0.125f;
                if (diag && ((tx << 2) + cc) >= ((ty << 2) + rr)) sv = -INFINITY;
                acc[rr][cc] = sv;
            }

        #pragma unroll
        for (int rr = 0; rr < 4; ++rr) {
            float mb = fmaxf(fmaxf(acc[rr][0], acc[rr][1]), fmaxf(acc[rr][2], acc[rr][3]));
            #pragma unroll
            for (int off = 1; off < 16; off <<= 1) mb = fmaxf(mb, __shfl_xor(mb, off));
            const float mn = fmaxf(m_run[rr], mb);
            const float mfix = (mn == -INFINITY) ? 0.f : mn;
            const float alpha = (m_run[rr] == -INFINITY) ? 0.f : __expf(m_run[rr] - mn);
            m_run[rr] = mn;
            const float p0 = __expf(acc[rr][0] - mfix);
            const float p1 = __expf(acc[rr][1] - mfix);
            const float p2 = __expf(acc[rr][2] - mfix);
            const float p3 = __expf(acc[rr][3] - mfix);
            float rs = p0 + p1 + p2 + p3;
            #pragma unroll
            for (int off = 1; off < 16; off <<= 1) rs += __shfl_xor(rs, off);
            l_run[rr] = l_run[rr] * alpha + rs;
            const int row = (ty << 2) + rr;
            Pt[(tx << 2) + 0][row] = p0;
            Pt[(tx << 2) + 1][row] = p1;
            Pt[(tx << 2) + 2][row] = p2;
            Pt[(tx << 2) + 3][row] = p3;
            o_acc[rr][0] *= alpha; o_acc[rr][1] *= alpha;
            o_acc[rr][2] *= alpha; o_acc[rr][3] *= alpha;
        }
        __syncthreads();

        #pragma unroll 8
        for (int j = 0; j < 64; ++j) {
            const float4 av = *(const float4*)&Pt[j][ty << 2];
            const float4 bv = *(const float4*)&KV[j][tx << 2];
            o_acc[0][0] += av.x * bv.x; o_acc[0][1] += av.x * bv.y; o_acc[0][2] += av.x * bv.z; o_acc[0][3] += av.x * bv.w;
            o_acc[1][0] += av.y * bv.x; o_acc[1][1] += av.y * bv.y; o_acc[1][2] += av.y * bv.z; o_acc[1][3] += av.y * bv.w;
            o_acc[2][0] += av.z * bv.x; o_acc[2][1] += av.z * bv.y; o_acc[2][2] += av.z * bv.z; o_acc[2][3] += av.z * bv.w;
            o_acc[3][0] += av.w * bv.x; o_acc[3][1] += av.w * bv.y; o_acc[3][2] += av.w * bv.z; o_acc[3][3] += av.w * bv.w;
        }
        __syncthreads();
    }

    u16* ctxb = ctx + ((size_t)b * 1024 + (size_t)it * 64) * 512 + h * 64;
    #pragma unroll
    for (int rr = 0; rr < 4; ++rr) {
        const int row = (ty << 2) + rr;
        const float inv = (l_run[rr] > 0.f) ? 1.f / l_run[rr] : 0.f;
        #pragma unroll
        for (int cc = 0; cc < 4; ++cc)
            ctxb[(size_t)row * 512 + (tx << 2) + cc] = f2bf(o_acc[rr][cc] * inv);
    }
}

__global__ void copy_kernel(const float* __restrict__ x, float* __restrict__ out)
{
    int idx = blockIdx.x * 256 + threadIdx.x;
    out[idx] = x[idx];
}

// ---------------------------------------------------------------------------
extern "C" void kernel_launch(void* const* d_in, const int* in_sizes, int n_in,
                              void* d_out, int out_size, void* d_ws, size_t ws_size,
                              hipStream_t stream)
{
    const float* q_raw   = (const float*)d_in[0];
    const float* m_seq   = (const float*)d_in[1];
    const float* qa      = (const float*)d_in[2];
    const float* exp_w1  = (const float*)d_in[3];
    const float* exp_b1  = (const float*)d_in[4];
    const float* exp_w2  = (const float*)d_in[5];
    const float* exp_b2  = (const float*)d_in[6];
    const float* adapt_w = (const float*)d_in[7];
    const float* adapt_b = (const float*)d_in[8];
    const float* gate_w  = (const float*)d_in[9];
    const float* gate_b  = (const float*)d_in[10];
    const float* moe_g   = (const float*)d_in[11];
    const float* moe_b   = (const float*)d_in[12];
    const float* kw      = (const float*)d_in[13];
    const float* kb      = (const float*)d_in[14];
    const float* vw      = (const float*)d_in[15];
    const float* vb      = (const float*)d_in[16];
    const float* ow      = (const float*)d_in[17];
    const float* ob      = (const float*)d_in[18];
    const float* ln1g    = (const float*)d_in[19];
    const float* ln1b    = (const float*)d_in[20];
    const float* fw1     = (const float*)d_in[21];
    const float* fb1     = (const float*)d_in[22];
    const float* fw2     = (const float*)d_in[23];
    const float* fb2     = (const float*)d_in[24];
    const float* ln2g    = (const float*)d_in[25];
    const float* ln2b    = (const float*)d_in[26];
    float* out = (float*)d_out;

    const size_t NEED = 78708736ull;
    if (ws_size < NEED) return;

    char* base = (char*)d_ws;
    float* x  = (float*)(base + 0);
    u16*  xb  = (u16*)(base + 8388608);
    u16*  yb  = (u16*)(base + 12582912);
    char* G = base + 16777216;
    // MoE-phase view
    u16*   q_bf    = (u16*)(G + 0);
    u16*   w1t     = (u16*)(G + 28311552);
    u16*   w2t     = (u16*)(G + 33030144);
    float* summary = (float*)(G + 28311552);   // aliases w1t/w2t after their death
    u16*   h1b     = (u16*)(G + 36700160);
    u16*   expb    = (u16*)(G + 42991616);
    float* pe      = (float*)(G + 59768832);
    float* gates   = (float*)(G + 61865984);
    // layer-phase view (MoE buffers dead)
    u16*   kwt  = (u16*)(G + 0);
    u16*   vwt  = (u16*)(G + 2097152);
    u16*   owt  = (u16*)(G + 4194304);
    u16*   fw1t = (u16*)(G + 6291456);
    u16*   fw2t = (u16*)(G + 14680064);
    u16*   khb  = (u16*)(G + 23068672);
    u16*   vhb  = (u16*)(G + 27262976);
    u16*   ctxb = (u16*)(G + 31457280);
    float* p    = (float*)(G + 35651584);
    u16*   ffhb = (u16*)(G + 44040192);

    pe_kernel<<<2048, 256, 0, stream>>>(pe);
    f2b_kernel<<<49152, 256, 0, stream>>>(q_raw, q_bf, 12582912);

    tconv_kernel<<<dim3(24, 24, 4), 256, 0, stream>>>(exp_w1, w1t, 768, 768);
    tconv_kernel<<<dim3(16, 24, 4), 256, 0, stream>>>(exp_w2, w2t, 768, 512);

    // ---- MoE phase ----
    for (int k = 0; k < 4; ++k) {
        gemm_bf16<<<dim3(6, 32), 256, 0, stream>>>(
            q_bf + k * 768, 3072, w1t + (size_t)k * 589824, 768,
            exp_b1 + k * 768, nullptr, h1b, 768, 768, 1);
        gemm_bf16<<<dim3(4, 32), 256, 0, stream>>>(
            h1b, 768, w2t + (size_t)k * 393216, 768,
            exp_b2 + k * 512, nullptr, expb + k * 512, 2048, 768, 0);
    }
    // gate path in fp32 (top-2 selection is discontinuous; must match np)
    gemm_tile<<<dim3(8, 64), 256, 0, stream>>>(
        q_raw, 3072, adapt_w, 512, adapt_b, summary, 512, 3072, 1);
    gate_kernel<<<4096, 64, 0, stream>>>(summary, m_seq, gate_w, gate_b, gates);
    moe_ln_kernel<<<4096, 64, 0, stream>>>(expb, gates, moe_g, moe_b, pe, x, xb);
    y_kernel<<<8192, 256, 0, stream>>>(qa, pe, yb);

    tconv_kernel<<<dim3(16, 16, 4), 256, 0, stream>>>(kw, kwt, 512, 512);
    tconv_kernel<<<dim3(16, 16, 4), 256, 0, stream>>>(vw, vwt, 512, 512);
    tconv_kernel<<<dim3(16, 16, 4), 256, 0, stream>>>(ow, owt, 512, 512);
    tconv_kernel<<<dim3(64, 16, 4), 256, 0, stream>>>(fw1, fw1t, 512, 2048);
    tconv_kernel<<<dim3(16, 64, 4), 256, 0, stream>>>(fw2, fw2t, 2048, 512);

    // ---- transformer layers ----
    for (int i = 0; i < 4; ++i) {
        gemm_bf16<<<dim3(4, 32), 256, 0, stream>>>(
            xb, 512, kwt + (size_t)i * 262144, 512, kb + i * 512,
            nullptr, khb, 512, 512, 0);
        gemm_bf16<<<dim3(4, 32), 256, 0, stream>>>(
            yb, 512, vwt + (size_t)i * 262144, 512, vb + i * 512,
            nullptr, vhb, 512, 512, 0);
        attn_kernel<<<dim3(4, 8, 16), 256, 0, stream>>>(khb, vhb, ctxb);
        gemm_bf16<<<dim3(4, 32), 256, 0, stream>>>(
            ctxb, 512, owt + (size_t)i * 262144, 512, ob + i * 512,
            p, nullptr, 512, 512, 0);
        add_ln_kernel<<<4096, 64, 0, stream>>>(x, xb, p, ln1g + i * 512, ln1b + i * 512);
        gemm_bf16<<<dim3(16, 32), 256, 0, stream>>>(
            xb, 512, fw1t + (size_t)i * 1048576, 512, fb1 + i * 2048,
            nullptr, ffhb, 2048, 512, 1);
        gemm_bf16<<<dim3(4, 32), 256, 0, stream>>>(
            ffhb, 2048, fw2t + (size_t)i * 1048576, 2048, fb2 + i * 512,
            p, nullptr, 512, 2048, 0);
        add_ln_kernel<<<4096, 64, 0, stream>>>(x, xb, p, ln2g + i * 512, ln2b + i * 512);
    }

    copy_kernel<<<8192, 256, 0, stream>>>(x, out);
}

// Round 7
// 1187.905 us; speedup vs baseline: 4.5167x; 1.2825x over previous
//
#include <hip/hip_runtime.h>
#include <hip/hip_bf16.h>

typedef unsigned short u16;
typedef __attribute__((ext_vector_type(8))) short short8;
typedef __attribute__((ext_vector_type(4))) float floatx4;

__device__ __forceinline__ float bf2f(u16 u) {
    unsigned x = (unsigned)u << 16;
    return __uint_as_float(x);
}
__device__ __forceinline__ u16 f2bf(float f) {   // round-to-nearest-even
    unsigned x = __float_as_uint(f);
    unsigned r = (x + 0x7fffu + ((x >> 16) & 1u)) >> 16;
    return (u16)r;
}

__device__ __forceinline__ float wave_sum(float v) {
    #pragma unroll
    for (int off = 32; off; off >>= 1) v += __shfl_xor(v, off);
    return v;
}

// staging helpers: 8 elems -> bf16 LDS
__device__ __forceinline__ void load8(const u16* p, u16* dst) {
    *(uint4*)dst = *(const uint4*)p;
}
__device__ __forceinline__ void load8(const float* p, u16* dst) {
    float4 a = *(const float4*)p, b = *(const float4*)(p + 4);
    dst[0] = f2bf(a.x); dst[1] = f2bf(a.y); dst[2] = f2bf(a.z); dst[3] = f2bf(a.w);
    dst[4] = f2bf(b.x); dst[5] = f2bf(b.y); dst[6] = f2bf(b.z); dst[7] = f2bf(b.w);
}

// ---------------------------------------------------------------------------
// bf16 MFMA GEMM, z-batched: C[M,N] = act(A[M,K] @ B[K,N] + bias[N]).
// Bt = B^T [N][K] bf16. A is bf16 or fp32 (converted in staging).
// 128x128 tile / 256 threads / 4 waves; fp32 accumulate.
// ---------------------------------------------------------------------------
template <typename TA>
__global__ __launch_bounds__(256) void gemm_bf16(
    const TA* __restrict__ A, int lda, long strideAz,
    const u16* __restrict__ Bt, int ldb, long strideBz,
    const float* __restrict__ bias, int strideBiasZ,
    float* __restrict__ Cf, u16* __restrict__ Cb, int ldc, long strideCz,
    int K, int act)
{
    __shared__ __align__(16) u16 Asm[128 * 32];
    __shared__ __align__(16) u16 Bsm[128 * 32];

    A += (size_t)blockIdx.z * strideAz;
    Bt += (size_t)blockIdx.z * strideBz;
    bias += (size_t)blockIdx.z * strideBiasZ;
    if (Cf) Cf += (size_t)blockIdx.z * strideCz;
    if (Cb) Cb += (size_t)blockIdx.z * strideCz;

    const int tid = threadIdx.x;
    const int lane = tid & 63;
    const int wave = tid >> 6;
    const int m0 = blockIdx.y * 128, n0 = blockIdx.x * 128;
    const int wm = (wave >> 1) * 64, wn = (wave & 1) * 64;

    const int r0 = tid >> 2;
    const int kc = (tid & 3) * 8;

    const int kq = (lane >> 4) * 8;
    const int fm = lane & 15;

    const floatx4 zz = {0.f, 0.f, 0.f, 0.f};
    floatx4 acc[4][4];
    #pragma unroll
    for (int mt = 0; mt < 4; ++mt)
        #pragma unroll
        for (int nt = 0; nt < 4; ++nt) acc[mt][nt] = zz;

    for (int kt = 0; kt < K; kt += 32) {
        load8(&A[(size_t)(m0 + r0) * lda + kt + kc],      &Asm[r0 * 32 + kc]);
        load8(&A[(size_t)(m0 + r0 + 64) * lda + kt + kc], &Asm[(r0 + 64) * 32 + kc]);
        load8(&Bt[(size_t)(n0 + r0) * ldb + kt + kc],      &Bsm[r0 * 32 + kc]);
        load8(&Bt[(size_t)(n0 + r0 + 64) * ldb + kt + kc], &Bsm[(r0 + 64) * 32 + kc]);
        __syncthreads();

        short8 af[4], bfr[4];
        #pragma unroll
        for (int mt = 0; mt < 4; ++mt)
            af[mt] = *(const short8*)&Asm[(wm + mt * 16 + fm) * 32 + kq];
        #pragma unroll
        for (int nt = 0; nt < 4; ++nt)
            bfr[nt] = *(const short8*)&Bsm[(wn + nt * 16 + fm) * 32 + kq];

        #pragma unroll
        for (int mt = 0; mt < 4; ++mt)
            #pragma unroll
            for (int nt = 0; nt < 4; ++nt)
                acc[mt][nt] = __builtin_amdgcn_mfma_f32_16x16x32_bf16(
                    af[mt], bfr[nt], acc[mt][nt], 0, 0, 0);
        __syncthreads();
    }

    const int cr = (lane >> 4) * 4;
    #pragma unroll
    for (int mt = 0; mt < 4; ++mt) {
        #pragma unroll
        for (int nt = 0; nt < 4; ++nt) {
            const int col = n0 + wn + nt * 16 + fm;
            const float bz = bias[col];
            #pragma unroll
            for (int r = 0; r < 4; ++r) {
                const int row = m0 + wm + mt * 16 + cr + r;
                float v = acc[mt][nt][r] + bz;
                if (act) v = fmaxf(v, 0.f);
                if (Cf) Cf[(size_t)row * ldc + col] = v;
                if (Cb) Cb[(size_t)row * ldc + col] = f2bf(v);
            }
        }
    }
}

// ---------------------------------------------------------------------------
// fp32 split-K GEMM partials (adapter/gate path must stay fp32 for top-k).
// grid (N/64, M/64, SPLIT); z computes K-range [z*kz, (z+1)*kz) -> psum + z*strideCz.
// ---------------------------------------------------------------------------
__global__ __launch_bounds__(256) void gemm_tile_splitk(
    const float* __restrict__ A, int lda,
    const float* __restrict__ Bm, int ldb,
    float* __restrict__ C, int ldc, long strideCz,
    int kz)
{
    __shared__ float As[16][68];
    __shared__ float Bs[16][64];

    const int tid = threadIdx.x;
    const int tx = tid & 15, ty = tid >> 4;
    const int rowBase = blockIdx.y * 64, colBase = blockIdx.x * 64;
    const int k0 = blockIdx.z * kz;
    C += (size_t)blockIdx.z * strideCz;

    const int ar = tid >> 2;
    const int ak = (tid & 3) << 2;
    const int bk = tid >> 4;
    const int bc = (tid & 15) << 2;

    float acc[4][4] = {};

    const float* aptr = A  + (size_t)(rowBase + ar) * lda + k0 + ak;
    const float* bptr = Bm + (size_t)(k0 + bk) * ldb + colBase + bc;

    for (int kt = 0; kt < kz; kt += 16) {
        const float4 a4 = *(const float4*)aptr;
        const float4 b4 = *(const float4*)bptr;
        As[ak + 0][ar] = a4.x; As[ak + 1][ar] = a4.y; As[ak + 2][ar] = a4.z; As[ak + 3][ar] = a4.w;
        *(float4*)&Bs[bk][bc] = b4;
        __syncthreads();
        #pragma unroll
        for (int kk = 0; kk < 16; ++kk) {
            const float4 av = *(const float4*)&As[kk][ty << 2];
            const float4 bv = *(const float4*)&Bs[kk][tx << 2];
            acc[0][0] += av.x * bv.x; acc[0][1] += av.x * bv.y; acc[0][2] += av.x * bv.z; acc[0][3] += av.x * bv.w;
            acc[1][0] += av.y * bv.x; acc[1][1] += av.y * bv.y; acc[1][2] += av.y * bv.z; acc[1][3] += av.y * bv.w;
            acc[2][0] += av.z * bv.x; acc[2][1] += av.z * bv.y; acc[2][2] += av.z * bv.z; acc[2][3] += av.z * bv.w;
            acc[3][0] += av.w * bv.x; acc[3][1] += av.w * bv.y; acc[3][2] += av.w * bv.z; acc[3][3] += av.w * bv.w;
        }
        __syncthreads();
        aptr += 16;
        bptr += (size_t)16 * ldb;
    }

    #pragma unroll
    for (int rr = 0; rr < 4; ++rr) {
        const int row = rowBase + (ty << 2) + rr;
        float* crow = C + (size_t)row * ldc + colBase + (tx << 2);
        #pragma unroll
        for (int cc = 0; cc < 4; ++cc) crow[cc] = acc[rr][cc];
    }
}

// summary = relu(psum0+psum1+psum2+psum3 + bias)  (4096x512)
__global__ void sum4_relu_kernel(const float* __restrict__ ps,
                                 const float* __restrict__ bias,
                                 float* __restrict__ out)
{
    int i = blockIdx.x * 256 + threadIdx.x;
    float v = ps[i] + ps[i + 2097152] + ps[i + 4194304] + ps[i + 6291456] + bias[i & 511];
    out[i] = fmaxf(v, 0.f);
}

// ---------------------------------------------------------------------------
// fp32 [K][N] -> bf16 [N][K] (transposed), batched. 32x32 tiles, 256 threads.
// ---------------------------------------------------------------------------
__global__ __launch_bounds__(256) void tconv_kernel(
    const float* __restrict__ in, u16* __restrict__ out, int K, int N)
{
    __shared__ float t[32][33];
    const int n0 = blockIdx.x * 32, k0 = blockIdx.y * 32;
    const size_t bo = (size_t)blockIdx.z * K * N;
    const int tx = threadIdx.x & 31, ty = threadIdx.x >> 5;
    const float* src = in + bo;
    u16* dst = out + bo;
    #pragma unroll
    for (int r = ty; r < 32; r += 8) t[r][tx] = src[(size_t)(k0 + r) * N + n0 + tx];
    __syncthreads();
    #pragma unroll
    for (int r = ty; r < 32; r += 8) dst[(size_t)(n0 + r) * K + k0 + tx] = f2bf(t[tx][r]);
}

// ---------------------------------------------------------------------------
__global__ void pe_kernel(float* __restrict__ pe)
{
    int idx = blockIdx.x * 256 + threadIdx.x;
    int s = idx >> 9, d = idx & 511;
    float div = expf((float)(d & ~1) * (-9.210340371976184f / 512.0f));
    float ang = (float)s * div;
    pe[idx] = (d & 1) ? cosf(ang) : sinf(ang);
}

__global__ void y_kernel(const float* __restrict__ qa, const float* __restrict__ pe,
                         u16* __restrict__ yb)
{
    int idx = blockIdx.x * 256 + threadIdx.x;
    yb[idx] = f2bf(qa[idx] + pe[idx & 524287]);
}

// ---------------------------------------------------------------------------
__global__ __launch_bounds__(64) void gate_kernel(
    const float* __restrict__ summary, const float* __restrict__ m_seq,
    const float* __restrict__ gw, const float* __restrict__ gb,
    float* __restrict__ gates)
{
    const int r = blockIdx.x, t = threadIdx.x;
    float p0 = 0.f, p1 = 0.f, p2 = 0.f, p3 = 0.f;
    const float* srow = summary + (size_t)r * 512;
    for (int j = t; j < 512; j += 64) {
        float s = srow[j];
        const float* g = gw + (size_t)j * 4;
        p0 += s * g[0]; p1 += s * g[1]; p2 += s * g[2]; p3 += s * g[3];
    }
    {
        float m = m_seq[(size_t)r * 64 + t];
        const float* g = gw + (size_t)(512 + t) * 4;
        p0 += m * g[0]; p1 += m * g[1]; p2 += m * g[2]; p3 += m * g[3];
    }
    p0 = wave_sum(p0); p1 = wave_sum(p1); p2 = wave_sum(p2); p3 = wave_sum(p3);
    if (t == 0) {
        float lg[4] = { p0 + gb[0], p1 + gb[1], p2 + gb[2], p3 + gb[3] };
        float m1 = -INFINITY, m2 = -INFINITY;
        #pragma unroll
        for (int k = 0; k < 4; ++k) {
            float v = lg[k];
            if (v > m1) { m2 = m1; m1 = v; }
            else if (v > m2) { m2 = v; }
        }
        float wv[4], s = 0.f;
        #pragma unroll
        for (int k = 0; k < 4; ++k) {
            wv[k] = (lg[k] >= m2) ? __expf(lg[k] - m1) : 0.f;
            s += wv[k];
        }
        float inv = 1.f / s;
        #pragma unroll
        for (int k = 0; k < 4; ++k) gates[(size_t)r * 4 + k] = wv[k] * inv;
    }
}

// ---------------------------------------------------------------------------
__global__ __launch_bounds__(64) void moe_ln_kernel(
    const u16* __restrict__ experts, const float* __restrict__ gates,
    const float* __restrict__ g, const float* __restrict__ bb,
    const float* __restrict__ pe, float* __restrict__ x, u16* __restrict__ xb)
{
    const int r = blockIdx.x, t = threadIdx.x;
    const u16* e = experts + (size_t)r * 2048;
    const float g0 = gates[r * 4 + 0], g1 = gates[r * 4 + 1];
    const float g2 = gates[r * 4 + 2], g3 = gates[r * 4 + 3];
    float v[8];
    #pragma unroll
    for (int it = 0; it < 8; ++it) {
        int d = t + it * 64;
        v[it] = g0 * bf2f(e[d]) + g1 * bf2f(e[512 + d])
              + g2 * bf2f(e[1024 + d]) + g3 * bf2f(e[1536 + d]);
    }
    float s = 0.f;
    #pragma unroll
    for (int it = 0; it < 8; ++it) s += v[it];
    s = wave_sum(s);
    const float mu = s * (1.f / 512.f);
    float q = 0.f;
    #pragma unroll
    for (int it = 0; it < 8; ++it) { float dd = v[it] - mu; q += dd * dd; }
    q = wave_sum(q);
    const float rstd = rsqrtf(q * (1.f / 512.f) + 1e-5f);
    const float* per = pe + (size_t)(r & 1023) * 512;
    #pragma unroll
    for (int it = 0; it < 8; ++it) {
        int d = t + it * 64;
        float o = (v[it] - mu) * rstd * g[d] + bb[d] + per[d];
        x[(size_t)r * 512 + d] = o;
        xb[(size_t)r * 512 + d] = f2bf(o);
    }
}

__global__ __launch_bounds__(64) void add_ln_kernel(
    float* __restrict__ x, u16* __restrict__ xb, const float* __restrict__ tbuf,
    const float* __restrict__ g, const float* __restrict__ bb)
{
    const int r = blockIdx.x, t = threadIdx.x;
    float* xr = x + (size_t)r * 512;
    const float* tr = tbuf + (size_t)r * 512;
    float v[8];
    #pragma unroll
    for (int it = 0; it < 8; ++it) { int d = t + it * 64; v[it] = xr[d] + tr[d]; }
    float s = 0.f;
    #pragma unroll
    for (int it = 0; it < 8; ++it) s += v[it];
    s = wave_sum(s);
    const float mu = s * (1.f / 512.f);
    float q = 0.f;
    #pragma unroll
    for (int it = 0; it < 8; ++it) { float dd = v[it] - mu; q += dd * dd; }
    q = wave_sum(q);
    const float rstd = rsqrtf(q * (1.f / 512.f) + 1e-5f);
    #pragma unroll
    for (int it = 0; it < 8; ++it) {
        int d = t + it * 64;
        float o = (v[it] - mu) * rstd * g[d] + bb[d];
        xr[d] = o;
        xb[(size_t)r * 512 + d] = f2bf(o);
    }
}

// ---------------------------------------------------------------------------
// MFMA flash strict-causal attention. Q=K=kh (bf16), V=vh (bf16), ctx bf16.
// Block = 256 thr (4 waves) per (b,h,64-row q-tile). Wave w: rows w*16..+15.
// Fragments (verified by passing gemm_bf16): A[m=lane&15][k=quad*8+j] from
// [m][k]-contig LDS; B same from B^T; C/D row=quad*4+reg, col=lane&15.
// P round-trips via LDS (C-layout -> A-layout). Vt/Ps stride 72 u16 keeps
// ds_read_b128 16B-aligned (144B rows).
// ---------------------------------------------------------------------------
__global__ __launch_bounds__(256) void attn_kernel(
    const u16* __restrict__ kh, const u16* __restrict__ vh,
    u16* __restrict__ ctx)
{
    __shared__ __align__(16) u16 Qs[64 * 64];   // [row][d]
    __shared__ __align__(16) u16 Ks[64 * 64];   // [key][d]
    __shared__ __align__(16) u16 Vt[64 * 72];   // [d][key]
    __shared__ __align__(16) u16 Ps[64 * 72];   // [row][key]

    const int tid = threadIdx.x;
    const int lane = tid & 63, wave = tid >> 6;
    const int quad = lane >> 4, fm = lane & 15;
    const int b = blockIdx.x, h = blockIdx.y;
    const int bz = blockIdx.z;
    const int it = (bz < 8) ? bz : (23 - bz);

    const u16* khb = kh + ((size_t)b * 1024) * 512 + h * 64;
    const u16* vhb = vh + ((size_t)b * 1024) * 512 + h * 64;

    const int lj = tid >> 2;    // 0..63 row
    const int lc = tid & 3;     // d-chunk of 16

    {   // Q tile [row][d]
        const u16* src = khb + (size_t)(it * 64 + lj) * 512 + lc * 16;
        *(uint4*)&Qs[lj * 64 + lc * 16]     = *(const uint4*)src;
        *(uint4*)&Qs[lj * 64 + lc * 16 + 8] = *(const uint4*)(src + 8);
    }

    const floatx4 zz = {0.f, 0.f, 0.f, 0.f};
    floatx4 o_acc[4];            // [d-tile nt]; lanes hold rows quad*4+r
    #pragma unroll
    for (int nt = 0; nt < 4; ++nt) o_acc[nt] = zz;
    float m_run[4] = { -INFINITY, -INFINITY, -INFINITY, -INFINITY };
    float l_run[4] = {};

    __syncthreads();

    for (int jt = 0; jt <= it; ++jt) {
        {   // stage K [key][d] + V transposed [d][key]
            const u16* ksrc = khb + (size_t)(jt * 64 + lj) * 512 + lc * 16;
            *(uint4*)&Ks[lj * 64 + lc * 16]     = *(const uint4*)ksrc;
            *(uint4*)&Ks[lj * 64 + lc * 16 + 8] = *(const uint4*)(ksrc + 8);
            const u16* vsrc = vhb + (size_t)(jt * 64 + lj) * 512 + lc * 16;
            uint4 v0 = *(const uint4*)vsrc, v1 = *(const uint4*)(vsrc + 8);
            const u16* e0 = (const u16*)&v0;
            const u16* e1 = (const u16*)&v1;
            #pragma unroll
            for (int e = 0; e < 8; ++e) Vt[(lc * 16 + e) * 72 + lj] = e0[e];
            #pragma unroll
            for (int e = 0; e < 8; ++e) Vt[(lc * 16 + 8 + e) * 72 + lj] = e1[e];
        }
        __syncthreads();

        // ---- QK^T: S[16 rows][64 cols] per wave ----
        floatx4 s_acc[4];
        #pragma unroll
        for (int nt = 0; nt < 4; ++nt) s_acc[nt] = zz;
        #pragma unroll
        for (int ks = 0; ks < 2; ++ks) {
            short8 af = *(const short8*)&Qs[(wave * 16 + fm) * 64 + ks * 32 + quad * 8];
            #pragma unroll
            for (int nt = 0; nt < 4; ++nt) {
                short8 bf = *(const short8*)&Ks[(nt * 16 + fm) * 64 + ks * 32 + quad * 8];
                s_acc[nt] = __builtin_amdgcn_mfma_f32_16x16x32_bf16(af, bf, s_acc[nt], 0, 0, 0);
            }
        }

        // ---- scale + strict mask + online softmax (rows quad*4+r) ----
        const bool diag = (jt == it);
        #pragma unroll
        for (int r = 0; r < 4; ++r) {
            const int rowi = wave * 16 + quad * 4 + r;   // row within q-tile
            float sv[4];
            #pragma unroll
            for (int nt = 0; nt < 4; ++nt) {
                float s = s_acc[nt][r] * 0.125f;
                if (diag && (nt * 16 + fm) >= rowi) s = -INFINITY;
                sv[nt] = s;
            }
            float mx = fmaxf(fmaxf(sv[0], sv[1]), fmaxf(sv[2], sv[3]));
            #pragma unroll
            for (int off = 1; off < 16; off <<= 1) mx = fmaxf(mx, __shfl_xor(mx, off));
            const float mn = fmaxf(m_run[r], mx);
            const float mfix = (mn == -INFINITY) ? 0.f : mn;
            const float alpha = (m_run[r] == -INFINITY) ? 0.f : __expf(m_run[r] - mn);
            m_run[r] = mn;
            float rs = 0.f;
            #pragma unroll
            for (int nt = 0; nt < 4; ++nt) {
                float p = __expf(sv[nt] - mfix);
                Ps[rowi * 72 + nt * 16 + fm] = f2bf(p);
                rs += p;
            }
            #pragma unroll
            for (int off = 1; off < 16; off <<= 1) rs += __shfl_xor(rs, off);
            l_run[r] = l_run[r] * alpha + rs;
            #pragma unroll
            for (int nt = 0; nt < 4; ++nt) o_acc[nt][r] *= alpha;
        }
        __syncthreads();   // Ps complete (Vt staged above)

        // ---- PV: O[16 rows][64 d] += P[16 rows][64 keys] @ V[64 keys][64 d] ----
        #pragma unroll
        for (int ks = 0; ks < 2; ++ks) {
            short8 af = *(const short8*)&Ps[(wave * 16 + fm) * 72 + ks * 32 + quad * 8];
            #pragma unroll
            for (int nt = 0; nt < 4; ++nt) {
                short8 bf = *(const short8*)&Vt[(nt * 16 + fm) * 72 + ks * 32 + quad * 8];
                o_acc[nt] = __builtin_amdgcn_mfma_f32_16x16x32_bf16(af, bf, o_acc[nt], 0, 0, 0);
            }
        }
        __syncthreads();   // done reading Ks/Vt/Ps before next staging
    }

    // ---- normalize + write ctx [row][d] bf16 ----
    u16* cb = ctx + ((size_t)b * 1024 + (size_t)it * 64 + wave * 16) * 512 + h * 64;
    #pragma unroll
    for (int r = 0; r < 4; ++r) {
        const int row = quad * 4 + r;
        const float inv = (l_run[r] > 0.f) ? 1.f / l_run[r] : 0.f;
        #pragma unroll
        for (int nt = 0; nt < 4; ++nt)
            cb[(size_t)row * 512 + nt * 16 + fm] = f2bf(o_acc[nt][r] * inv);
    }
}

__global__ void copy_kernel(const float* __restrict__ x, float* __restrict__ out)
{
    int idx = blockIdx.x * 256 + threadIdx.x;
    out[idx] = x[idx];
}

// ---------------------------------------------------------------------------
extern "C" void kernel_launch(void* const* d_in, const int* in_sizes, int n_in,
                              void* d_out, int out_size, void* d_ws, size_t ws_size,
                              hipStream_t stream)
{
    const float* q_raw   = (const float*)d_in[0];
    const float* m_seq   = (const float*)d_in[1];
    const float* qa      = (const float*)d_in[2];
    const float* exp_w1  = (const float*)d_in[3];
    const float* exp_b1  = (const float*)d_in[4];
    const float* exp_w2  = (const float*)d_in[5];
    const float* exp_b2  = (const float*)d_in[6];
    const float* adapt_w = (const float*)d_in[7];
    const float* adapt_b = (const float*)d_in[8];
    const float* gate_w  = (const float*)d_in[9];
    const float* gate_b  = (const float*)d_in[10];
    const float* moe_g   = (const float*)d_in[11];
    const float* moe_b   = (const float*)d_in[12];
    const float* kw      = (const float*)d_in[13];
    const float* kb      = (const float*)d_in[14];
    const float* vw      = (const float*)d_in[15];
    const float* vb      = (const float*)d_in[16];
    const float* ow      = (const float*)d_in[17];
    const float* ob      = (const float*)d_in[18];
    const float* ln1g    = (const float*)d_in[19];
    const float* ln1b    = (const float*)d_in[20];
    const float* fw1     = (const float*)d_in[21];
    const float* fb1     = (const float*)d_in[22];
    const float* fw2     = (const float*)d_in[23];
    const float* fb2     = (const float*)d_in[24];
    const float* ln2g    = (const float*)d_in[25];
    const float* ln2b    = (const float*)d_in[26];
    float* out = (float*)d_out;

    const size_t NEED = 78708736ull;   // unchanged (proven)
    if (ws_size < NEED) return;

    char* base = (char*)d_ws;
    float* x  = (float*)(base + 0);            // 8,388,608
    u16*  xb  = (u16*)(base + 8388608);        // 4,194,304
    u16*  yb  = (u16*)(base + 12582912);       // 4,194,304
    char* G = base + 16777216;
    // ---- MoE phase ----
    u16*   w1t     = (u16*)(G + 0);            // 4,718,592
    u16*   w2t     = (u16*)(G + 4718592);      // 3,145,728
    // stage A (adapter/gate):
    float* psum    = (float*)(G + 7864320);    // 4 x 4096x512 x4B = 33,554,432
    float* summary = (float*)(G + 33030144);   // 8,388,608  (dead before stage B)
    // stage B (experts) — same region, disjoint lifetime:
    u16*   h1b4    = (u16*)(G + 7864320);      // 4 x 4096x768 x2B = 25,165,824
    u16*   expb    = (u16*)(G + 33030144);     // 16,777,216
    float* pe      = (float*)(G + 49807360);   // 2,097,152
    float* gates   = (float*)(G + 51904512);   //    65,536
    // ---- layer phase (MoE buffers dead) ----
    u16*   kwt  = (u16*)(G + 0);               // 2,097,152
    u16*   vwt  = (u16*)(G + 2097152);
    u16*   owt  = (u16*)(G + 4194304);
    u16*   fw1t = (u16*)(G + 6291456);         // 8,388,608
    u16*   fw2t = (u16*)(G + 14680064);        // 8,388,608
    u16*   khb  = (u16*)(G + 23068672);        // 4,194,304
    u16*   vhb  = (u16*)(G + 27262976);
    u16*   ctxb = (u16*)(G + 31457280);
    float* p    = (float*)(G + 35651584);      // 8,388,608
    u16*   ffhb = (u16*)(G + 44040192);        // 16,777,216

    pe_kernel<<<2048, 256, 0, stream>>>(pe);
    tconv_kernel<<<dim3(24, 24, 4), 256, 0, stream>>>(exp_w1, w1t, 768, 768);
    tconv_kernel<<<dim3(16, 24, 4), 256, 0, stream>>>(exp_w2, w2t, 768, 512);

    // ---- adapter + gate (fp32, split-K=4 for occupancy) ----
    gemm_tile_splitk<<<dim3(8, 64, 4), 256, 0, stream>>>(
        q_raw, 3072, adapt_w, 512, psum, 512, 2097152L, 768);
    sum4_relu_kernel<<<8192, 256, 0, stream>>>(psum, adapt_b, summary);
    gate_kernel<<<4096, 64, 0, stream>>>(summary, m_seq, gate_w, gate_b, gates);

    // ---- experts (z-batched; A read fp32 + inline bf16 convert) ----
    gemm_bf16<float><<<dim3(6, 32, 4), 256, 0, stream>>>(
        q_raw, 3072, 768L, w1t, 768, 589824L, exp_b1, 768,
        nullptr, h1b4, 768, 3145728L, 768, 1);
    gemm_bf16<u16><<<dim3(4, 32, 4), 256, 0, stream>>>(
        h1b4, 768, 3145728L, w2t, 768, 393216L, exp_b2, 512,
        nullptr, expb, 2048, 512L, 768, 0);
    moe_ln_kernel<<<4096, 64, 0, stream>>>(expb, gates, moe_g, moe_b, pe, x, xb);
    y_kernel<<<8192, 256, 0, stream>>>(qa, pe, yb);

    // ---- layer weight conversions ----
    tconv_kernel<<<dim3(16, 16, 4), 256, 0, stream>>>(kw, kwt, 512, 512);
    tconv_kernel<<<dim3(16, 16, 4), 256, 0, stream>>>(vw, vwt, 512, 512);
    tconv_kernel<<<dim3(16, 16, 4), 256, 0, stream>>>(ow, owt, 512, 512);
    tconv_kernel<<<dim3(64, 16, 4), 256, 0, stream>>>(fw1, fw1t, 512, 2048);
    tconv_kernel<<<dim3(16, 64, 4), 256, 0, stream>>>(fw2, fw2t, 2048, 512);

    // ---- transformer layers ----
    for (int i = 0; i < 4; ++i) {
        gemm_bf16<u16><<<dim3(4, 32), 256, 0, stream>>>(
            xb, 512, 0L, kwt + (size_t)i * 262144, 512, 0L, kb + i * 512, 0,
            nullptr, khb, 512, 0L, 512, 0);
        gemm_bf16<u16><<<dim3(4, 32), 256, 0, stream>>>(
            yb, 512, 0L, vwt + (size_t)i * 262144, 512, 0L, vb + i * 512, 0,
            nullptr, vhb, 512, 0L, 512, 0);
        attn_kernel<<<dim3(4, 8, 16), 256, 0, stream>>>(khb, vhb, ctxb);
        gemm_bf16<u16><<<dim3(4, 32), 256, 0, stream>>>(
            ctxb, 512, 0L, owt + (size_t)i * 262144, 512, 0L, ob + i * 512, 0,
            p, nullptr, 512, 0L, 512, 0);
        add_ln_kernel<<<4096, 64, 0, stream>>>(x, xb, p, ln1g + i * 512, ln1b + i * 512);
        gemm_bf16<u16><<<dim3(16, 32), 256, 0, stream>>>(
            xb, 512, 0L, fw1t + (size_t)i * 1048576, 512, 0L, fb1 + i * 2048, 0,
            nullptr, ffhb, 2048, 0L, 512, 1);
        gemm_bf16<u16><<<dim3(4, 32), 256, 0, stream>>>(
            ffhb, 2048, 0L, fw2t + (size_t)i * 1048576, 2048, 0L, fb2 + i * 512, 0,
            p, nullptr, 512, 0L, 2048, 0);
        add_ln_kernel<<<4096, 64, 0, stream>>>(x, xb, p, ln2g + i * 512, ln2b + i * 512);
    }

    copy_kernel<<<8192, 256, 0, stream>>>(x, out);
}

// Round 8
// 1171.620 us; speedup vs baseline: 4.5795x; 1.0139x over previous
//
#include <hip/hip_runtime.h>
#include <hip/hip_bf16.h>

typedef unsigned short u16;
typedef __attribute__((ext_vector_type(8))) short short8;
typedef __attribute__((ext_vector_type(4))) float floatx4;

template <typename T> struct is_u16 { static constexpr bool v = false; };
template <> struct is_u16<u16> { static constexpr bool v = true; };

__device__ __forceinline__ float bf2f(u16 u) {
    unsigned x = (unsigned)u << 16;
    return __uint_as_float(x);
}
__device__ __forceinline__ u16 f2bf(float f) {   // round-to-nearest-even
    unsigned x = __float_as_uint(f);
    unsigned r = (x + 0x7fffu + ((x >> 16) & 1u)) >> 16;
    return (u16)r;
}

__device__ __forceinline__ float wave_sum(float v) {
    #pragma unroll
    for (int off = 32; off; off >>= 1) v += __shfl_xor(v, off);
    return v;
}

// async global->LDS, 16B per lane; lds base must be wave-uniform (HW adds lane*16)
__device__ __forceinline__ void async16(const u16* g, const u16* lds) {
    __builtin_amdgcn_global_load_lds(
        (const __attribute__((address_space(1))) void*)g,
        (__attribute__((address_space(3))) void*)lds, 16, 0, 0);
}

// manual fp32 -> bf16 staging (8 elems)
__device__ __forceinline__ void load8f(const float* p, u16* dst) {
    float4 a = *(const float4*)p, b = *(const float4*)(p + 4);
    dst[0] = f2bf(a.x); dst[1] = f2bf(a.y); dst[2] = f2bf(a.z); dst[3] = f2bf(a.w);
    dst[4] = f2bf(b.x); dst[5] = f2bf(b.y); dst[6] = f2bf(b.z); dst[7] = f2bf(b.w);
}

// ---------------------------------------------------------------------------
// bf16 MFMA GEMM, z-batched: C = act(A @ B + bias). Bt = B^T [N][K] bf16.
// 128x128 tile / 256 threads / 4 waves. u16-A path stages via
// global_load_lds width=16 (LDS addr == tid*16 B, wave-uniform base + lane*16).
// transC: Cb written V-transposed: Cb[((row>>10)*512+col)*1024 + (row&1023)].
// ---------------------------------------------------------------------------
template <typename TA>
__global__ __launch_bounds__(256) void gemm_bf16(
    const TA* __restrict__ A, int lda, long strideAz,
    const u16* __restrict__ Bt, int ldb, long strideBz,
    const float* __restrict__ bias, int strideBiasZ,
    float* __restrict__ Cf, u16* __restrict__ Cb, int ldc, long strideCz,
    int K, int act, int transC)
{
    __shared__ __align__(16) u16 Asm[128 * 32];
    __shared__ __align__(16) u16 Bsm[128 * 32];

    A += (size_t)blockIdx.z * strideAz;
    Bt += (size_t)blockIdx.z * strideBz;
    if (bias) bias += (size_t)blockIdx.z * strideBiasZ;
    if (Cf) Cf += (size_t)blockIdx.z * strideCz;
    if (Cb) Cb += (size_t)blockIdx.z * strideCz;

    const int tid = threadIdx.x;
    const int lane = tid & 63;
    const int wave = tid >> 6;
    const int m0 = blockIdx.y * 128, n0 = blockIdx.x * 128;
    const int wm = (wave >> 1) * 64, wn = (wave & 1) * 64;

    const int r0 = tid >> 2;
    const int kc = (tid & 3) * 8;

    const int kq = (lane >> 4) * 8;
    const int fm = lane & 15;

    const floatx4 zz = {0.f, 0.f, 0.f, 0.f};
    floatx4 acc[4][4];
    #pragma unroll
    for (int mt = 0; mt < 4; ++mt)
        #pragma unroll
        for (int nt = 0; nt < 4; ++nt) acc[mt][nt] = zz;

    const u16* ldsA0 = Asm + wave * 512;         // + lane*16B implicit
    const u16* ldsA1 = Asm + 2048 + wave * 512;
    const u16* ldsB0 = Bsm + wave * 512;
    const u16* ldsB1 = Bsm + 2048 + wave * 512;

    for (int kt = 0; kt < K; kt += 32) {
        if constexpr (is_u16<TA>::v) {
            async16(&A[(size_t)(m0 + r0) * lda + kt + kc],      ldsA0);
            async16(&A[(size_t)(m0 + r0 + 64) * lda + kt + kc], ldsA1);
            async16(&Bt[(size_t)(n0 + r0) * ldb + kt + kc],      ldsB0);
            async16(&Bt[(size_t)(n0 + r0 + 64) * ldb + kt + kc], ldsB1);
        } else {
            load8f(&A[(size_t)(m0 + r0) * lda + kt + kc],      &Asm[r0 * 32 + kc]);
            load8f(&A[(size_t)(m0 + r0 + 64) * lda + kt + kc], &Asm[(r0 + 64) * 32 + kc]);
            *(uint4*)&Bsm[r0 * 32 + kc]        = *(const uint4*)&Bt[(size_t)(n0 + r0) * ldb + kt + kc];
            *(uint4*)&Bsm[(r0 + 64) * 32 + kc] = *(const uint4*)&Bt[(size_t)(n0 + r0 + 64) * ldb + kt + kc];
        }
        __syncthreads();

        short8 af[4], bfr[4];
        #pragma unroll
        for (int mt = 0; mt < 4; ++mt)
            af[mt] = *(const short8*)&Asm[(wm + mt * 16 + fm) * 32 + kq];
        #pragma unroll
        for (int nt = 0; nt < 4; ++nt)
            bfr[nt] = *(const short8*)&Bsm[(wn + nt * 16 + fm) * 32 + kq];

        #pragma unroll
        for (int mt = 0; mt < 4; ++mt)
            #pragma unroll
            for (int nt = 0; nt < 4; ++nt)
                acc[mt][nt] = __builtin_amdgcn_mfma_f32_16x16x32_bf16(
                    af[mt], bfr[nt], acc[mt][nt], 0, 0, 0);
        __syncthreads();
    }

    const int cr = (lane >> 4) * 4;
    #pragma unroll
    for (int mt = 0; mt < 4; ++mt) {
        #pragma unroll
        for (int nt = 0; nt < 4; ++nt) {
            const int col = n0 + wn + nt * 16 + fm;
            const float bz = bias ? bias[col] : 0.f;
            #pragma unroll
            for (int r = 0; r < 4; ++r) {
                const int row = m0 + wm + mt * 16 + cr + r;
                float v = acc[mt][nt][r] + bz;
                if (act) v = fmaxf(v, 0.f);
                if (Cf) Cf[(size_t)row * ldc + col] = v;
                if (Cb) {
                    if (transC)
                        Cb[(((size_t)(row >> 10) * 512 + col) << 10) + (row & 1023)] = f2bf(v);
                    else
                        Cb[(size_t)row * ldc + col] = f2bf(v);
                }
            }
        }
    }
}

// ---------------------------------------------------------------------------
// fp32 split-K GEMM partials (gate path stays fp32: top-k is discontinuous).
// ---------------------------------------------------------------------------
__global__ __launch_bounds__(256) void gemm_tile_splitk(
    const float* __restrict__ A, int lda,
    const float* __restrict__ Bm, int ldb,
    float* __restrict__ C, int ldc, long strideCz,
    int kz)
{
    __shared__ float As[16][68];
    __shared__ float Bs[16][64];

    const int tid = threadIdx.x;
    const int tx = tid & 15, ty = tid >> 4;
    const int rowBase = blockIdx.y * 64, colBase = blockIdx.x * 64;
    const int k0 = blockIdx.z * kz;
    C += (size_t)blockIdx.z * strideCz;

    const int ar = tid >> 2;
    const int ak = (tid & 3) << 2;
    const int bk = tid >> 4;
    const int bc = (tid & 15) << 2;

    float acc[4][4] = {};

    const float* aptr = A  + (size_t)(rowBase + ar) * lda + k0 + ak;
    const float* bptr = Bm + (size_t)(k0 + bk) * ldb + colBase + bc;

    for (int kt = 0; kt < kz; kt += 16) {
        const float4 a4 = *(const float4*)aptr;
        const float4 b4 = *(const float4*)bptr;
        As[ak + 0][ar] = a4.x; As[ak + 1][ar] = a4.y; As[ak + 2][ar] = a4.z; As[ak + 3][ar] = a4.w;
        *(float4*)&Bs[bk][bc] = b4;
        __syncthreads();
        #pragma unroll
        for (int kk = 0; kk < 16; ++kk) {
            const float4 av = *(const float4*)&As[kk][ty << 2];
            const float4 bv = *(const float4*)&Bs[kk][tx << 2];
            acc[0][0] += av.x * bv.x; acc[0][1] += av.x * bv.y; acc[0][2] += av.x * bv.z; acc[0][3] += av.x * bv.w;
            acc[1][0] += av.y * bv.x; acc[1][1] += av.y * bv.y; acc[1][2] += av.y * bv.z; acc[1][3] += av.y * bv.w;
            acc[2][0] += av.z * bv.x; acc[2][1] += av.z * bv.y; acc[2][2] += av.z * bv.z; acc[2][3] += av.z * bv.w;
            acc[3][0] += av.w * bv.x; acc[3][1] += av.w * bv.y; acc[3][2] += av.w * bv.z; acc[3][3] += av.w * bv.w;
        }
        __syncthreads();
        aptr += 16;
        bptr += (size_t)16 * ldb;
    }

    #pragma unroll
    for (int rr = 0; rr < 4; ++rr) {
        const int row = rowBase + (ty << 2) + rr;
        float* crow = C + (size_t)row * ldc + colBase + (tx << 2);
        #pragma unroll
        for (int cc = 0; cc < 4; ++cc) crow[cc] = acc[rr][cc];
    }
}

__global__ void sum4_relu_kernel(const float* __restrict__ ps,
                                 const float* __restrict__ bias,
                                 float* __restrict__ out)
{
    int i = blockIdx.x * 256 + threadIdx.x;
    float v = ps[i] + ps[i + 2097152] + ps[i + 4194304] + ps[i + 6291456] + bias[i & 511];
    out[i] = fmaxf(v, 0.f);
}

// ---------------------------------------------------------------------------
__global__ __launch_bounds__(256) void tconv_kernel(
    const float* __restrict__ in, u16* __restrict__ out, int K, int N)
{
    __shared__ float t[32][33];
    const int n0 = blockIdx.x * 32, k0 = blockIdx.y * 32;
    const size_t bo = (size_t)blockIdx.z * K * N;
    const int tx = threadIdx.x & 31, ty = threadIdx.x >> 5;
    const float* src = in + bo;
    u16* dst = out + bo;
    #pragma unroll
    for (int r = ty; r < 32; r += 8) t[r][tx] = src[(size_t)(k0 + r) * N + n0 + tx];
    __syncthreads();
    #pragma unroll
    for (int r = ty; r < 32; r += 8) dst[(size_t)(n0 + r) * K + k0 + tx] = f2bf(t[tx][r]);
}

// ---------------------------------------------------------------------------
__global__ void pe_kernel(float* __restrict__ pe)
{
    int idx = blockIdx.x * 256 + threadIdx.x;
    int s = idx >> 9, d = idx & 511;
    float div = expf((float)(d & ~1) * (-9.210340371976184f / 512.0f));
    float ang = (float)s * div;
    pe[idx] = (d & 1) ? cosf(ang) : sinf(ang);
}

__global__ void y_kernel(const float* __restrict__ qa, const float* __restrict__ pe,
                         u16* __restrict__ yb)
{
    int idx = blockIdx.x * 256 + threadIdx.x;
    yb[idx] = f2bf(qa[idx] + pe[idx & 524287]);
}

// ---------------------------------------------------------------------------
__global__ __launch_bounds__(64) void gate_kernel(
    const float* __restrict__ summary, const float* __restrict__ m_seq,
    const float* __restrict__ gw, const float* __restrict__ gb,
    float* __restrict__ gates)
{
    const int r = blockIdx.x, t = threadIdx.x;
    float p0 = 0.f, p1 = 0.f, p2 = 0.f, p3 = 0.f;
    const float* srow = summary + (size_t)r * 512;
    for (int j = t; j < 512; j += 64) {
        float s = srow[j];
        const float* g = gw + (size_t)j * 4;
        p0 += s * g[0]; p1 += s * g[1]; p2 += s * g[2]; p3 += s * g[3];
    }
    {
        float m = m_seq[(size_t)r * 64 + t];
        const float* g = gw + (size_t)(512 + t) * 4;
        p0 += m * g[0]; p1 += m * g[1]; p2 += m * g[2]; p3 += m * g[3];
    }
    p0 = wave_sum(p0); p1 = wave_sum(p1); p2 = wave_sum(p2); p3 = wave_sum(p3);
    if (t == 0) {
        float lg[4] = { p0 + gb[0], p1 + gb[1], p2 + gb[2], p3 + gb[3] };
        float m1 = -INFINITY, m2 = -INFINITY;
        #pragma unroll
        for (int k = 0; k < 4; ++k) {
            float v = lg[k];
            if (v > m1) { m2 = m1; m1 = v; }
            else if (v > m2) { m2 = v; }
        }
        float wv[4], s = 0.f;
        #pragma unroll
        for (int k = 0; k < 4; ++k) {
            wv[k] = (lg[k] >= m2) ? __expf(lg[k] - m1) : 0.f;
            s += wv[k];
        }
        float inv = 1.f / s;
        #pragma unroll
        for (int k = 0; k < 4; ++k) gates[(size_t)r * 4 + k] = wv[k] * inv;
    }
}

// ---------------------------------------------------------------------------
__global__ __launch_bounds__(64) void moe_ln_kernel(
    const u16* __restrict__ experts, const float* __restrict__ gates,
    const float* __restrict__ g, const float* __restrict__ bb,
    const float* __restrict__ pe, float* __restrict__ x, u16* __restrict__ xb)
{
    const int r = blockIdx.x, t = threadIdx.x;
    const u16* e = experts + (size_t)r * 2048;
    const float g0 = gates[r * 4 + 0], g1 = gates[r * 4 + 1];
    const float g2 = gates[r * 4 + 2], g3 = gates[r * 4 + 3];
    float v[8];
    #pragma unroll
    for (int it = 0; it < 8; ++it) {
        int d = t + it * 64;
        v[it] = g0 * bf2f(e[d]) + g1 * bf2f(e[512 + d])
              + g2 * bf2f(e[1024 + d]) + g3 * bf2f(e[1536 + d]);
    }
    float s = 0.f;
    #pragma unroll
    for (int it = 0; it < 8; ++it) s += v[it];
    s = wave_sum(s);
    const float mu = s * (1.f / 512.f);
    float q = 0.f;
    #pragma unroll
    for (int it = 0; it < 8; ++it) { float dd = v[it] - mu; q += dd * dd; }
    q = wave_sum(q);
    const float rstd = rsqrtf(q * (1.f / 512.f) + 1e-5f);
    const float* per = pe + (size_t)(r & 1023) * 512;
    #pragma unroll
    for (int it = 0; it < 8; ++it) {
        int d = t + it * 64;
        float o = (v[it] - mu) * rstd * g[d] + bb[d] + per[d];
        x[(size_t)r * 512 + d] = o;
        xb[(size_t)r * 512 + d] = f2bf(o);
    }
}

// x = LN(x + t0 [+ t1] [+ bias])*g + b; writes x fp32, xb bf16, optional out2.
__global__ __launch_bounds__(64) void add_ln_kernel(
    float* __restrict__ x, u16* __restrict__ xb,
    const float* __restrict__ t0, const float* __restrict__ t1,
    const float* __restrict__ bias,
    const float* __restrict__ g, const float* __restrict__ bb,
    float* __restrict__ out2)
{
    const int r = blockIdx.x, t = threadIdx.x;
    float* xr = x + (size_t)r * 512;
    float v[8];
    #pragma unroll
    for (int it = 0; it < 8; ++it) {
        int d = t + it * 64;
        float tv = t0[(size_t)r * 512 + d];
        if (t1) tv += t1[(size_t)r * 512 + d];
        if (bias) tv += bias[d];
        v[it] = xr[d] + tv;
    }
    float s = 0.f;
    #pragma unroll
    for (int it = 0; it < 8; ++it) s += v[it];
    s = wave_sum(s);
    const float mu = s * (1.f / 512.f);
    float q = 0.f;
    #pragma unroll
    for (int it = 0; it < 8; ++it) { float dd = v[it] - mu; q += dd * dd; }
    q = wave_sum(q);
    const float rstd = rsqrtf(q * (1.f / 512.f) + 1e-5f);
    #pragma unroll
    for (int it = 0; it < 8; ++it) {
        int d = t + it * 64;
        float o = (v[it] - mu) * rstd * g[d] + bb[d];
        xr[d] = o;
        xb[(size_t)r * 512 + d] = f2bf(o);
        if (out2) out2[(size_t)r * 512 + d] = o;
    }
}

// ---------------------------------------------------------------------------
// MFMA flash strict-causal attention. Q=K=kh (bf16, [token][h*64+d]),
// V=vhT (bf16, pre-transposed: vhT[(b*512 + h*64 + d)*1024 + s]), ctx bf16.
// ---------------------------------------------------------------------------
__global__ __launch_bounds__(256) void attn_kernel(
    const u16* __restrict__ kh, const u16* __restrict__ vhT,
    u16* __restrict__ ctx)
{
    __shared__ __align__(16) u16 Qs[64 * 64];   // [row][d]
    __shared__ __align__(16) u16 Ks[64 * 64];   // [key][d]
    __shared__ __align__(16) u16 Vt[64 * 72];   // [d][key] (stride 72 = 144B, 16B-mult)
    __shared__ __align__(16) u16 Ps[64 * 72];   // [row][key]

    const int tid = threadIdx.x;
    const int lane = tid & 63, wave = tid >> 6;
    const int quad = lane >> 4, fm = lane & 15;
    const int b = blockIdx.x, h = blockIdx.y;
    const int bz = blockIdx.z;
    const int it = (bz < 8) ? bz : (23 - bz);

    const u16* khb = kh + ((size_t)b * 1024) * 512 + h * 64;
    const u16* vtb = vhT + ((size_t)(b * 512 + h * 64)) * 1024;

    const int lj = tid >> 2;    // 0..63
    const int lc = tid & 3;

    {   // Q tile [row][d]
        const u16* src = khb + (size_t)(it * 64 + lj) * 512 + lc * 16;
        *(uint4*)&Qs[lj * 64 + lc * 16]     = *(const uint4*)src;
        *(uint4*)&Qs[lj * 64 + lc * 16 + 8] = *(const uint4*)(src + 8);
    }

    const floatx4 zz = {0.f, 0.f, 0.f, 0.f};
    floatx4 o_acc[4];
    #pragma unroll
    for (int nt = 0; nt < 4; ++nt) o_acc[nt] = zz;
    float m_run[4] = { -INFINITY, -INFINITY, -INFINITY, -INFINITY };
    float l_run[4] = {};

    __syncthreads();

    for (int jt = 0; jt <= it; ++jt) {
        {   // K [key][d] natural; V [d][key] direct from vhT (vectorized)
            const u16* ksrc = khb + (size_t)(jt * 64 + lj) * 512 + lc * 16;
            *(uint4*)&Ks[lj * 64 + lc * 16]     = *(const uint4*)ksrc;
            *(uint4*)&Ks[lj * 64 + lc * 16 + 8] = *(const uint4*)(ksrc + 8);
            const u16* vsrc = vtb + (size_t)lj * 1024 + jt * 64 + lc * 16;
            *(uint4*)&Vt[lj * 72 + lc * 16]     = *(const uint4*)vsrc;
            *(uint4*)&Vt[lj * 72 + lc * 16 + 8] = *(const uint4*)(vsrc + 8);
        }
        __syncthreads();

        // ---- QK^T ----
        floatx4 s_acc[4];
        #pragma unroll
        for (int nt = 0; nt < 4; ++nt) s_acc[nt] = zz;
        #pragma unroll
        for (int ks = 0; ks < 2; ++ks) {
            short8 af = *(const short8*)&Qs[(wave * 16 + fm) * 64 + ks * 32 + quad * 8];
            #pragma unroll
            for (int nt = 0; nt < 4; ++nt) {
                short8 bf = *(const short8*)&Ks[(nt * 16 + fm) * 64 + ks * 32 + quad * 8];
                s_acc[nt] = __builtin_amdgcn_mfma_f32_16x16x32_bf16(af, bf, s_acc[nt], 0, 0, 0);
            }
        }

        // ---- scale + strict mask + online softmax ----
        const bool diag = (jt == it);
        #pragma unroll
        for (int r = 0; r < 4; ++r) {
            const int rowi = wave * 16 + quad * 4 + r;
            float sv[4];
            #pragma unroll
            for (int nt = 0; nt < 4; ++nt) {
                float s = s_acc[nt][r] * 0.125f;
                if (diag && (nt * 16 + fm) >= rowi) s = -INFINITY;
                sv[nt] = s;
            }
            float mx = fmaxf(fmaxf(sv[0], sv[1]), fmaxf(sv[2], sv[3]));
            #pragma unroll
            for (int off = 1; off < 16; off <<= 1) mx = fmaxf(mx, __shfl_xor(mx, off));
            const float mn = fmaxf(m_run[r], mx);
            const float mfix = (mn == -INFINITY) ? 0.f : mn;
            const float alpha = (m_run[r] == -INFINITY) ? 0.f : __expf(m_run[r] - mn);
            m_run[r] = mn;
            float rs = 0.f;
            #pragma unroll
            for (int nt = 0; nt < 4; ++nt) {
                float p = __expf(sv[nt] - mfix);
                Ps[rowi * 72 + nt * 16 + fm] = f2bf(p);
                rs += p;
            }
            #pragma unroll
            for (int off = 1; off < 16; off <<= 1) rs += __shfl_xor(rs, off);
            l_run[r] = l_run[r] * alpha + rs;
            #pragma unroll
            for (int nt = 0; nt < 4; ++nt) o_acc[nt][r] *= alpha;
        }
        __syncthreads();

        // ---- PV ----
        #pragma unroll
        for (int ks = 0; ks < 2; ++ks) {
            short8 af = *(const short8*)&Ps[(wave * 16 + fm) * 72 + ks * 32 + quad * 8];
            #pragma unroll
            for (int nt = 0; nt < 4; ++nt) {
                short8 bf = *(const short8*)&Vt[(nt * 16 + fm) * 72 + ks * 32 + quad * 8];
                o_acc[nt] = __builtin_amdgcn_mfma_f32_16x16x32_bf16(af, bf, o_acc[nt], 0, 0, 0);
            }
        }
        __syncthreads();
    }

    u16* cb = ctx + ((size_t)b * 1024 + (size_t)it * 64 + wave * 16) * 512 + h * 64;
    #pragma unroll
    for (int r = 0; r < 4; ++r) {
        const int row = quad * 4 + r;
        const float inv = (l_run[r] > 0.f) ? 1.f / l_run[r] : 0.f;
        #pragma unroll
        for (int nt = 0; nt < 4; ++nt)
            cb[(size_t)row * 512 + nt * 16 + fm] = f2bf(o_acc[nt][r] * inv);
    }
}

// ---------------------------------------------------------------------------
extern "C" void kernel_launch(void* const* d_in, const int* in_sizes, int n_in,
                              void* d_out, int out_size, void* d_ws, size_t ws_size,
                              hipStream_t stream)
{
    const float* q_raw   = (const float*)d_in[0];
    const float* m_seq   = (const float*)d_in[1];
    const float* qa      = (const float*)d_in[2];
    const float* exp_w1  = (const float*)d_in[3];
    const float* exp_b1  = (const float*)d_in[4];
    const float* exp_w2  = (const float*)d_in[5];
    const float* exp_b2  = (const float*)d_in[6];
    const float* adapt_w = (const float*)d_in[7];
    const float* adapt_b = (const float*)d_in[8];
    const float* gate_w  = (const float*)d_in[9];
    const float* gate_b  = (const float*)d_in[10];
    const float* moe_g   = (const float*)d_in[11];
    const float* moe_b   = (const float*)d_in[12];
    const float* kw      = (const float*)d_in[13];
    const float* kb      = (const float*)d_in[14];
    const float* vw      = (const float*)d_in[15];
    const float* vb      = (const float*)d_in[16];
    const float* ow      = (const float*)d_in[17];
    const float* ob      = (const float*)d_in[18];
    const float* ln1g    = (const float*)d_in[19];
    const float* ln1b    = (const float*)d_in[20];
    const float* fw1     = (const float*)d_in[21];
    const float* fb1     = (const float*)d_in[22];
    const float* fw2     = (const float*)d_in[23];
    const float* fb2     = (const float*)d_in[24];
    const float* ln2g    = (const float*)d_in[25];
    const float* ln2b    = (const float*)d_in[26];
    float* out = (float*)d_out;

    const size_t NEED = 78708736ull;
    if (ws_size < NEED) return;

    char* base = (char*)d_ws;
    float* x  = (float*)(base + 0);
    u16*  xb  = (u16*)(base + 8388608);
    u16*  yb  = (u16*)(base + 12582912);
    char* G = base + 16777216;
    // ---- MoE phase ----
    u16*   w1t     = (u16*)(G + 0);
    u16*   w2t     = (u16*)(G + 4718592);
    float* psum    = (float*)(G + 7864320);
    float* summary = (float*)(G + 33030144);
    u16*   h1b4    = (u16*)(G + 7864320);      // over psum (disjoint lifetime)
    u16*   expb    = (u16*)(G + 33030144);
    float* pe      = (float*)(G + 49807360);
    float* gates   = (float*)(G + 51904512);
    // ---- layer phase ----
    u16*   kwt  = (u16*)(G + 0);
    u16*   vwt  = (u16*)(G + 2097152);
    u16*   owt  = (u16*)(G + 4194304);
    u16*   fw1t = (u16*)(G + 6291456);
    u16*   fw2t = (u16*)(G + 14680064);
    u16*   khb  = (u16*)(G + 23068672);
    u16*   vhT  = (u16*)(G + 27262976);
    u16*   ctxb = (u16*)(G + 31457280);
    float* p    = (float*)(G + 35651584);
    u16*   ffhb = (u16*)(G + 44040192);
    // FFN2 split-K partials (khb/vhT/ctxb/p all dead during FFN2)
    float* ps0  = (float*)(G + 23068672);      // 2 x 2097152 floats

    pe_kernel<<<2048, 256, 0, stream>>>(pe);
    tconv_kernel<<<dim3(24, 24, 4), 256, 0, stream>>>(exp_w1, w1t, 768, 768);
    tconv_kernel<<<dim3(16, 24, 4), 256, 0, stream>>>(exp_w2, w2t, 768, 512);

    // ---- adapter + gate (fp32) ----
    gemm_tile_splitk<<<dim3(8, 64, 4), 256, 0, stream>>>(
        q_raw, 3072, adapt_w, 512, psum, 512, 2097152L, 768);
    sum4_relu_kernel<<<8192, 256, 0, stream>>>(psum, adapt_b, summary);
    gate_kernel<<<4096, 64, 0, stream>>>(summary, m_seq, gate_w, gate_b, gates);

    // ---- experts ----
    gemm_bf16<float><<<dim3(6, 32, 4), 256, 0, stream>>>(
        q_raw, 3072, 768L, w1t, 768, 589824L, exp_b1, 768,
        nullptr, h1b4, 768, 3145728L, 768, 1, 0);
    gemm_bf16<u16><<<dim3(4, 32, 4), 256, 0, stream>>>(
        h1b4, 768, 3145728L, w2t, 768, 393216L, exp_b2, 512,
        nullptr, expb, 2048, 512L, 768, 0, 0);
    moe_ln_kernel<<<4096, 64, 0, stream>>>(expb, gates, moe_g, moe_b, pe, x, xb);
    y_kernel<<<8192, 256, 0, stream>>>(qa, pe, yb);

    // ---- layer weight conversions ----
    tconv_kernel<<<dim3(16, 16, 4), 256, 0, stream>>>(kw, kwt, 512, 512);
    tconv_kernel<<<dim3(16, 16, 4), 256, 0, stream>>>(vw, vwt, 512, 512);
    tconv_kernel<<<dim3(16, 16, 4), 256, 0, stream>>>(ow, owt, 512, 512);
    tconv_kernel<<<dim3(64, 16, 4), 256, 0, stream>>>(fw1, fw1t, 512, 2048);
    tconv_kernel<<<dim3(16, 64, 4), 256, 0, stream>>>(fw2, fw2t, 2048, 512);

    // ---- transformer layers ----
    for (int i = 0; i < 4; ++i) {
        gemm_bf16<u16><<<dim3(4, 32), 256, 0, stream>>>(
            xb, 512, 0L, kwt + (size_t)i * 262144, 512, 0L, kb + i * 512, 0,
            nullptr, khb, 512, 0L, 512, 0, 0);
        gemm_bf16<u16><<<dim3(4, 32), 256, 0, stream>>>(
            yb, 512, 0L, vwt + (size_t)i * 262144, 512, 0L, vb + i * 512, 0,
            nullptr, vhT, 512, 0L, 512, 0, 1);           // transposed C-write
        attn_kernel<<<dim3(4, 8, 16), 256, 0, stream>>>(khb, vhT, ctxb);
        gemm_bf16<u16><<<dim3(4, 32), 256, 0, stream>>>(
            ctxb, 512, 0L, owt + (size_t)i * 262144, 512, 0L, ob + i * 512, 0,
            p, nullptr, 512, 0L, 512, 0, 0);
        add_ln_kernel<<<4096, 64, 0, stream>>>(
            x, xb, p, nullptr, nullptr, ln1g + i * 512, ln1b + i * 512, nullptr);
        gemm_bf16<u16><<<dim3(16, 32), 256, 0, stream>>>(
            xb, 512, 0L, fw1t + (size_t)i * 1048576, 512, 0L, fb1 + i * 2048, 0,
            nullptr, ffhb, 2048, 0L, 512, 1, 0);
        gemm_bf16<u16><<<dim3(4, 32, 2), 256, 0, stream>>>(   // split-K=2
            ffhb, 2048, 1024L, fw2t + (size_t)i * 1048576, 2048, 1024L, nullptr, 0,
            ps0, nullptr, 512, 2097152L, 1024, 0, 0);
        add_ln_kernel<<<4096, 64, 0, stream>>>(
            x, xb, ps0, ps0 + 2097152, fb2 + i * 512,
            ln2g + i * 512, ln2b + i * 512, (i == 3) ? out : nullptr);
    }
}